// Round 8
// baseline (125.440 us; speedup 1.0000x reference)
//
#include <hip/hip_runtime.h>

typedef __bf16 bf16;
typedef __bf16 bf16x8 __attribute__((ext_vector_type(8)));
typedef float  f32x4  __attribute__((ext_vector_type(4)));

#define MFMA16(a, b, c) __builtin_amdgcn_mfma_f32_16x16x32_bf16((a), (b), (c), 0, 0, 0)

#define GLOAD16(gp, lp) __builtin_amdgcn_global_load_lds( \
    (const __attribute__((address_space(1))) void*)(gp),  \
    (__attribute__((address_space(3))) void*)(lp), 16, 0, 0)

#define BAR __builtin_amdgcn_s_barrier()
#define WAITV8 asm volatile("s_waitcnt vmcnt(8)" ::: "memory")
#define WAITV0 asm volatile("s_waitcnt vmcnt(0)" ::: "memory")

// ==== 256x256 8-phase NT GEMM with one-phase register read-ahead ====
// C(MxN) = A(MxK) @ B(NxK)^T, 3-bit XOR LDS swizzle, counted vmcnt(8)
template <typename CT>
__global__ __launch_bounds__(512, 2) void gemm256(const bf16* __restrict__ A,
                                                  const bf16* __restrict__ B,
                                                  CT* __restrict__ C,
                                                  int M, int N, int K) {
    __shared__ bf16 sA[2][256 * 64];
    __shared__ bf16 sB[2][256 * 64];
    const int tid = threadIdx.x, lane = tid & 63, w = tid >> 6;
    const int wm = w >> 2, wn = w & 3;                 // 2 M-waves x 4 N-waves

    // XCD-aware bijective block swizzle (nwg % 8 == 0)
    const int nwg = gridDim.x * gridDim.y;
    const int lin = blockIdx.y * gridDim.x + blockIdx.x;
    const int cpx = nwg >> 3;
    const int swzb = (lin & 7) * cpx + (lin >> 3);
    const int row0 = (swzb / gridDim.x) * 256, col0 = (swzb % gridDim.x) * 256;
    const int nt = K >> 6;

    // 3-bit row-XOR swizzle: LDS[r][c] holds global[r][c ^ (r&7)*8]
    const int sw3   = (lane & 7) * 8;
    const int s0    = (lane >> 4) * 8;
    const int koff0 = s0 ^ sw3;
    const int koff1 = (s0 | 32) ^ sw3;
    const int aoff = (wm * 128 + (lane & 15)) * 64;
    const int boff = (wn * 64  + (lane & 15)) * 64;

    auto stgA = [&](int slot, int t, int i) {          // linear LDS dst, inverse-swizzled src
        int c = i * 512 + tid;
        int r = c >> 3;
        int c8 = ((c & 7) * 8) ^ ((r & 7) * 8);
        GLOAD16(A + (size_t)(row0 + r) * K + t * 64 + c8, &sA[slot][c * 8]);
    };
    auto stgB = [&](int slot, int t, int i) {
        int c = i * 512 + tid;
        int r = c >> 3;
        int c8 = ((c & 7) * 8) ^ ((r & 7) * 8);
        GLOAD16(B + (size_t)(col0 + r) * K + t * 64 + c8, &sB[slot][c * 8]);
    };

    f32x4 acc[8][4] = {};
    bf16x8 a[4][2], b[2][2], a2[4][2], b2[2][2];

    // prologue: stage tile0 (8) + tile1 (8); drain tile0; preload tile0's P1 frags
    #pragma unroll
    for (int i = 0; i < 4; ++i) stgA(0, 0, i);
    #pragma unroll
    for (int i = 0; i < 4; ++i) stgB(0, 0, i);
    #pragma unroll
    for (int i = 0; i < 4; ++i) stgA(1, 1, i);
    #pragma unroll
    for (int i = 0; i < 4; ++i) stgB(1, 1, i);
    WAITV8;
    BAR;
    {
        const bf16* sa = sA[0];
        const bf16* sb = sB[0];
        #pragma unroll
        for (int mi = 0; mi < 4; ++mi) {
            a[mi][0] = *(const bf16x8*)&sa[aoff + mi * 1024 + koff0];
            a[mi][1] = *(const bf16x8*)&sa[aoff + mi * 1024 + koff1];
        }
        #pragma unroll
        for (int ni = 0; ni < 2; ++ni) {
            b[ni][0] = *(const bf16x8*)&sb[boff + ni * 1024 + koff0];
            b[ni][1] = *(const bf16x8*)&sb[boff + ni * 1024 + koff1];
        }
    }

    for (int j = 0; j < nt; ++j) {
        const int s = j & 1;
        const bf16* sa = sA[s];
        const bf16* sb = sB[s];
        const bf16* san = sA[s ^ 1];
        const bf16* sbn = sB[s ^ 1];

        // ---- P1: issue B n2-3 reads (for P2); MFMA (m0-3, n0-1) on a,b
        #pragma unroll
        for (int ni = 0; ni < 2; ++ni) {
            b2[ni][0] = *(const bf16x8*)&sb[boff + (ni + 2) * 1024 + koff0];
            b2[ni][1] = *(const bf16x8*)&sb[boff + (ni + 2) * 1024 + koff1];
        }
        BAR;
        __builtin_amdgcn_s_setprio(1);
        #pragma unroll
        for (int mi = 0; mi < 4; ++mi)
            #pragma unroll
            for (int ni = 0; ni < 2; ++ni) {
                acc[mi][ni] = MFMA16(a[mi][0], b[ni][0], acc[mi][ni]);
                acc[mi][ni] = MFMA16(a[mi][1], b[ni][1], acc[mi][ni]);
            }
        __builtin_amdgcn_s_setprio(0);
        BAR;

        // ---- P2: issue A m4-7 reads (for P3); MFMA (m0-3, n2-3) on a,b2
        #pragma unroll
        for (int mi = 0; mi < 4; ++mi) {
            a2[mi][0] = *(const bf16x8*)&sa[aoff + (mi + 4) * 1024 + koff0];
            a2[mi][1] = *(const bf16x8*)&sa[aoff + (mi + 4) * 1024 + koff1];
        }
        BAR;
        __builtin_amdgcn_s_setprio(1);
        #pragma unroll
        for (int mi = 0; mi < 4; ++mi)
            #pragma unroll
            for (int ni = 0; ni < 2; ++ni) {
                acc[mi][ni + 2] = MFMA16(a[mi][0], b2[ni][0], acc[mi][ni + 2]);
                acc[mi][ni + 2] = MFMA16(a[mi][1], b2[ni][1], acc[mi][ni + 2]);
            }
        __builtin_amdgcn_s_setprio(0);
        BAR;

        // ---- P3: stage B(j+2) (B(s) reads fully drained by P2); MFMA (m4-7, n0-1) on a2,b
        if (j + 2 < nt) {
            #pragma unroll
            for (int i = 0; i < 4; ++i) stgB(s, j + 2, i);
        }
        BAR;
        __builtin_amdgcn_s_setprio(1);
        #pragma unroll
        for (int mi = 0; mi < 4; ++mi)
            #pragma unroll
            for (int ni = 0; ni < 2; ++ni) {
                acc[mi + 4][ni] = MFMA16(a2[mi][0], b[ni][0], acc[mi + 4][ni]);
                acc[mi + 4][ni] = MFMA16(a2[mi][1], b[ni][1], acc[mi + 4][ni]);
            }
        __builtin_amdgcn_s_setprio(0);
        BAR;

        // ---- P4: stage A(j+2); counted vmcnt(8) -> tile j+1 landed; barrier;
        //          issue next-tile P1 reads (a,b from slot s^1); MFMA (m4-7, n2-3) on a2,b2
        if (j + 2 < nt) {
            #pragma unroll
            for (int i = 0; i < 4; ++i) stgA(s, j + 2, i);
            WAITV8;                  // leaves tile j+2's 8 in flight, drains tile j+1
        } else if (j + 1 < nt) {
            WAITV0;                  // j == nt-2: tile nt-1 fully landed
        }
        BAR;                         // collective fence: tile j+1 visible to all waves
        if (j + 1 < nt) {
            #pragma unroll
            for (int mi = 0; mi < 4; ++mi) {
                a[mi][0] = *(const bf16x8*)&san[aoff + mi * 1024 + koff0];
                a[mi][1] = *(const bf16x8*)&san[aoff + mi * 1024 + koff1];
            }
            #pragma unroll
            for (int ni = 0; ni < 2; ++ni) {
                b[ni][0] = *(const bf16x8*)&sbn[boff + ni * 1024 + koff0];
                b[ni][1] = *(const bf16x8*)&sbn[boff + ni * 1024 + koff1];
            }
            __builtin_amdgcn_sched_barrier(0);   // pin read issue above the MFMA cluster
        }
        __builtin_amdgcn_s_setprio(1);
        #pragma unroll
        for (int mi = 0; mi < 4; ++mi)
            #pragma unroll
            for (int ni = 0; ni < 2; ++ni) {
                acc[mi + 4][ni + 2] = MFMA16(a2[mi][0], b2[ni][0], acc[mi + 4][ni + 2]);
                acc[mi + 4][ni + 2] = MFMA16(a2[mi][1], b2[ni][1], acc[mi + 4][ni + 2]);
            }
        __builtin_amdgcn_s_setprio(0);
        BAR;
    }

    const int crow = row0 + wm * 128 + (lane >> 4) * 4;
    const int ccol = col0 + wn * 64 + (lane & 15);
    #pragma unroll
    for (int mi = 0; mi < 8; ++mi)
        #pragma unroll
        for (int ni = 0; ni < 4; ++ni)
            #pragma unroll
            for (int r = 0; r < 4; ++r)
                C[(size_t)(crow + mi * 16 + r) * N + ccol + ni * 16] = (CT)acc[mi][ni][r];
}

// ---- NT GEMM (m97 structure, 128^2) with 3-bit XOR swizzle + XCD block swizzle ----
template <typename CT>
__global__ __launch_bounds__(256) void gemm_nt(const bf16* __restrict__ A,
                                               const bf16* __restrict__ B,
                                               CT* __restrict__ C, int M, int N, int K) {
    __shared__ __align__(16) bf16 As[128 * 64];
    __shared__ __align__(16) bf16 Bs[128 * 64];
    const int tid  = threadIdx.x;
    const int lane = tid & 63;
    const int w    = tid >> 6;
    const int wm   = w >> 1, wn = w & 1;

    const int nwg = gridDim.x * gridDim.y;
    const int lin = blockIdx.y * gridDim.x + blockIdx.x;
    const int cpx = nwg >> 3;
    const int swzb = (lin & 7) * cpx + (lin >> 3);
    const int row0 = (swzb / gridDim.x) * 128, col0 = (swzb % gridDim.x) * 128;

    const int sr   = tid >> 3, sc = (tid & 7) * 8;
    const int sw3   = (lane & 7) * 8;
    const int s0    = (lane >> 4) * 8;
    const int kcs[2] = { s0 ^ sw3, (s0 | 32) ^ sw3 };

    f32x4 acc[4][4] = {};

    for (int k0 = 0; k0 < K; k0 += 64) {
        __syncthreads();
        #pragma unroll
        for (int i = 0; i < 4; ++i) {
            int r = sr + i * 32;
            int c8 = sc ^ ((r & 7) * 8);
            GLOAD16(A + (size_t)(row0 + r) * K + k0 + c8, &As[(i * 256 + tid) * 8]);
            GLOAD16(B + (size_t)(col0 + r) * K + k0 + c8, &Bs[(i * 256 + tid) * 8]);
        }
        __syncthreads();
        #pragma unroll
        for (int kk = 0; kk < 2; ++kk) {
            const int kc = kcs[kk];
            bf16x8 af[4], bfr[4];
            #pragma unroll
            for (int mi = 0; mi < 4; ++mi)
                af[mi] = *(const bf16x8*)&As[(wm * 64 + mi * 16 + (lane & 15)) * 64 + kc];
            #pragma unroll
            for (int ni = 0; ni < 4; ++ni)
                bfr[ni] = *(const bf16x8*)&Bs[(wn * 64 + ni * 16 + (lane & 15)) * 64 + kc];
            #pragma unroll
            for (int mi = 0; mi < 4; ++mi)
                #pragma unroll
                for (int ni = 0; ni < 4; ++ni)
                    acc[mi][ni] = MFMA16(af[mi], bfr[ni], acc[mi][ni]);
        }
    }
    const int crow = row0 + wm * 64 + (lane >> 4) * 4;
    const int ccol = col0 + wn * 64 + (lane & 15);
    #pragma unroll
    for (int mi = 0; mi < 4; ++mi)
        #pragma unroll
        for (int ni = 0; ni < 4; ++ni)
            #pragma unroll
            for (int r = 0; r < 4; ++r)
                C[(size_t)(crow + mi * 16 + r) * N + ccol + ni * 16] = (CT)acc[mi][ni][r];
}

// ---------------- fused f32 -> bf16 bulk convert (x, W_qkv, W_out) ----------------
__global__ __launch_bounds__(256) void cvt3_k(const float* __restrict__ x,
                                              const float* __restrict__ wq,
                                              const float* __restrict__ wo,
                                              bf16* __restrict__ xbf,
                                              bf16* __restrict__ wqkv,
                                              bf16* __restrict__ wout) {
    int i = blockIdx.x * 256 + threadIdx.x;          // 0 .. 1048575
    const float* in; bf16* out; int off;
    if (i < 524288)       { in = x;  out = xbf;  off = i; }
    else if (i < 917504)  { in = wq; out = wqkv; off = i - 524288; }
    else                  { in = wo; out = wout; off = i - 917504; }
    f32x4 a = *(const f32x4*)(in + (size_t)off * 8);
    f32x4 b = *(const f32x4*)(in + (size_t)off * 8 + 4);
    bf16x8 o;
    o[0] = (bf16)a[0]; o[1] = (bf16)a[1]; o[2] = (bf16)a[2]; o[3] = (bf16)a[3];
    o[4] = (bf16)b[0]; o[5] = (bf16)b[1]; o[6] = (bf16)b[2]; o[7] = (bf16)b[3];
    *(bf16x8*)(out + (size_t)off * 8) = o;
}

// ---- fused: blocks 0-255 = q row-softmax; blocks 256-511 = exp(k) partial sums ----
__global__ __launch_bounds__(256) void qsA_k(bf16* __restrict__ qkv, float* __restrict__ part) {
    if (blockIdx.x < 256) {
        int tg = blockIdx.x * 256 + threadIdx.x;   // 0..65535
        int h = tg & 15, r = tg >> 4;
        bf16* q = qkv + (size_t)r * 3072 + h * 64;
        bf16x8 buf[8];
        float v[64];
        #pragma unroll
        for (int i = 0; i < 8; ++i) buf[i] = *(const bf16x8*)(q + i * 8);
        float m = -3.0e38f;
        #pragma unroll
        for (int i = 0; i < 8; ++i)
            #pragma unroll
            for (int e = 0; e < 8; ++e) { v[i * 8 + e] = (float)buf[i][e]; m = fmaxf(m, v[i * 8 + e]); }
        float s = 0.f;
        #pragma unroll
        for (int i = 0; i < 64; ++i) { v[i] = expf(v[i] - m); s += v[i]; }
        float inv = 0.125f / s;
        #pragma unroll
        for (int i = 0; i < 8; ++i) {
            bf16x8 o;
            #pragma unroll
            for (int e = 0; e < 8; ++e) o[e] = (bf16)(v[i * 8 + e] * inv);
            *(bf16x8*)(q + i * 8) = o;
        }
    } else {
        int blk = (blockIdx.x - 256) * 4 + (threadIdx.x >> 6);   // 0..1023
        int bh = blk >> 5, seg = blk & 31;
        int b = bh >> 4, h = bh & 15;
        int c = threadIdx.x & 63;
        const bf16* kb = qkv + (size_t)b * 2048 * 3072 + 1024 + h * 64 + c;
        float s = 0.f;
        for (int t0 = seg * 64; t0 < seg * 64 + 64; t0 += 8) {
            float e[8];
            #pragma unroll
            for (int u = 0; u < 8; ++u) e[u] = (float)kb[(size_t)(t0 + u) * 3072];
            #pragma unroll
            for (int u = 0; u < 8; ++u) s += expf(e[u]);
        }
        part[blk * 64 + c] = s;
    }
}

// -------- carry-in sweep: q -> qn = qsm/(kcum+eps), k -> exp(k), in place, 8-batched --------
__global__ __launch_bounds__(64) void scanB_k(bf16* __restrict__ qkv, const float* __restrict__ part) {
    int blk = blockIdx.x;
    int bh = blk >> 5, seg = blk & 31;
    int b = bh >> 4, h = bh & 15;
    int c = threadIdx.x;
    bf16* qb = qkv + (size_t)b * 2048 * 3072 + h * 64 + c;
    bf16* kb = qb + 1024;
    float run = 0.f;
    for (int i = 0; i < seg; ++i) run += part[(bh * 32 + i) * 64 + c];
    for (int t0 = seg * 64; t0 < seg * 64 + 64; t0 += 8) {
        float e[8], qv[8];
        #pragma unroll
        for (int u = 0; u < 8; ++u) e[u] = (float)kb[(size_t)(t0 + u) * 3072];
        #pragma unroll
        for (int u = 0; u < 8; ++u) qv[u] = (float)qb[(size_t)(t0 + u) * 3072];
        #pragma unroll
        for (int u = 0; u < 8; ++u) {
            e[u] = expf(e[u]);
            run += e[u];
            qv[u] = qv[u] / (run + 1e-9f);
        }
        #pragma unroll
        for (int u = 0; u < 8; ++u) {
            qb[(size_t)(t0 + u) * 3072] = (bf16)qv[u];
            kb[(size_t)(t0 + u) * 3072] = (bf16)e[u];
        }
    }
}

// -------- phase 1: per-chunk KV state  Wc[d][c] = sum_s V[s,d]*kexp[s,c]  (f32) --------
__global__ __launch_bounds__(256) void kvchunk_k(const bf16* __restrict__ qkv, float* __restrict__ Wc) {
    __shared__ bf16 KT[64][136];
    __shared__ bf16 VT[64][136];
    const int blk = blockIdx.x, bh = blk >> 4, j = blk & 15;
    const int b = bh >> 4, h = bh & 15;
    const int tid = threadIdx.x, lane = tid & 63, w = tid >> 6;
    const bf16* kbase = qkv + (size_t)(b * 2048 + j * 128) * 3072 + 1024 + h * 64;
    const bf16* vbase = kbase + 1024;

    #pragma unroll
    for (int i = 0; i < 4; ++i) {
        int idx = i * 256 + tid;
        int s = idx >> 3, cg = (idx & 7) * 8;
        bf16x8 k8 = *(const bf16x8*)(kbase + (size_t)s * 3072 + cg);
        bf16x8 v8 = *(const bf16x8*)(vbase + (size_t)s * 3072 + cg);
        #pragma unroll
        for (int e = 0; e < 8; ++e) {
            int d = cg + e;
            int sw2 = s ^ (((d >> 3) & 7) << 3);
            KT[d][sw2] = k8[e];
            VT[d][sw2] = v8[e];
        }
    }
    __syncthreads();

    f32x4 acc[4] = {};
    const int dr = w * 16 + (lane & 15);
    const int swd = ((dr >> 3) & 7) << 3;
    #pragma unroll
    for (int ks = 0; ks < 4; ++ks) {
        const int sc = ks * 32 + (lane >> 4) * 8;
        bf16x8 av = *(const bf16x8*)&VT[dr][sc ^ swd];
        #pragma unroll
        for (int ni = 0; ni < 4; ++ni) {
            int cr = ni * 16 + (lane & 15);
            bf16x8 bk = *(const bf16x8*)&KT[cr][sc ^ (((cr >> 3) & 7) << 3)];
            acc[ni] = MFMA16(av, bk, acc[ni]);
        }
    }
    float* out = Wc + (size_t)blk * 4096;
    const int dw = w * 16 + (lane >> 4) * 4;
    #pragma unroll
    for (int ni = 0; ni < 4; ++ni)
        #pragma unroll
        for (int r = 0; r < 4; ++r)
            out[(dw + r) * 64 + ni * 16 + (lane & 15)] = acc[ni][r];
}

// -------- phase 2: exclusive cumsum of chunk states across 16 chunks, f32 -> bf16 --------
__global__ __launch_bounds__(256) void kvscan_k(const float* __restrict__ Wc, bf16* __restrict__ Wpre) {
    int e = blockIdx.x * 256 + threadIdx.x;     // 131072
    int bh = e >> 12, off = e & 4095;
    float run = 0.f;
    #pragma unroll
    for (int j = 0; j < 16; ++j) {
        size_t idx = (size_t)(bh * 16 + j) * 4096 + off;
        Wpre[idx] = (bf16)run;
        run += Wc[idx];
    }
}

// -------- phase 3: O = qn @ Wpre (far) + masked (qn@K^T) @ V (near), one tile/block --------
__global__ __launch_bounds__(256) void attn2_k(const bf16* __restrict__ qkv,
                                               const bf16* __restrict__ Wpre,
                                               bf16* __restrict__ xo) {
    __shared__ bf16 Ks[128][72];
    __shared__ bf16 VTs[64][136];
    __shared__ bf16 Ss[128][136];
    const int bh = blockIdx.y, b = bh >> 4, h = bh & 15;
    const int ti = blockIdx.x, t0 = ti * 128;
    const int tid = threadIdx.x, lane = tid & 63, w = tid >> 6;
    const bf16* qn = qkv + (size_t)b * 2048 * 3072 + h * 64;
    const bf16* ke = qn + 1024;
    const bf16* vv = qn + 2048;

    bf16x8 qf[2][2];
    #pragma unroll
    for (int mi = 0; mi < 2; ++mi)
        #pragma unroll
        for (int kk = 0; kk < 2; ++kk)
            qf[mi][kk] = *(const bf16x8*)(qn + (size_t)(t0 + w * 32 + mi * 16 + (lane & 15)) * 3072
                                          + kk * 32 + (lane >> 4) * 8);
    const bf16* wp = Wpre + (size_t)(bh * 16 + ti) * 4096;
    bf16x8 wf[4][2];
    #pragma unroll
    for (int ni = 0; ni < 4; ++ni)
        #pragma unroll
        for (int kk = 0; kk < 2; ++kk)
            wf[ni][kk] = *(const bf16x8*)(wp + (ni * 16 + (lane & 15)) * 64 + kk * 32 + (lane >> 4) * 8);

    #pragma unroll
    for (int i = 0; i < 4; ++i) {
        int idx = i * 256 + tid;
        int s = idx >> 3, cg = (idx & 7) * 8;
        *(f32x4*)&Ks[s][cg] = *(const f32x4*)(ke + (size_t)(t0 + s) * 3072 + cg);
        bf16x8 v8 = *(const bf16x8*)(vv + (size_t)(t0 + s) * 3072 + cg);
        #pragma unroll
        for (int e = 0; e < 8; ++e) {
            int d = cg + e;
            VTs[d][s ^ (((d >> 3) & 7) << 3)] = v8[e];
        }
    }
    __syncthreads();

    f32x4 accO[2][4] = {};
    #pragma unroll
    for (int kk = 0; kk < 2; ++kk)
        #pragma unroll
        for (int mi = 0; mi < 2; ++mi)
            #pragma unroll
            for (int ni = 0; ni < 4; ++ni)
                accO[mi][ni] = MFMA16(qf[mi][kk], wf[ni][kk], accO[mi][ni]);

    f32x4 accS[2][8] = {};
    #pragma unroll
    for (int kk = 0; kk < 2; ++kk) {
        const int kc = kk * 32 + (lane >> 4) * 8;
        bf16x8 kf[8];
        #pragma unroll
        for (int ni = 0; ni < 8; ++ni) kf[ni] = *(const bf16x8*)&Ks[ni * 16 + (lane & 15)][kc];
        #pragma unroll
        for (int mi = 0; mi < 2; ++mi)
            #pragma unroll
            for (int ni = 0; ni < 8; ++ni)
                accS[mi][ni] = MFMA16(qf[mi][kk], kf[ni], accS[mi][ni]);
    }
    #pragma unroll
    for (int mi = 0; mi < 2; ++mi)
        #pragma unroll
        for (int ni = 0; ni < 8; ++ni) {
            const int tb = w * 32 + mi * 16 + (lane >> 4) * 4;
            const int sb = ni * 16 + (lane & 15);
            #pragma unroll
            for (int r = 0; r < 4; ++r) {
                float sv = accS[mi][ni][r];
                if (sb > tb + r) sv = 0.f;
                Ss[tb + r][sb] = (bf16)sv;
            }
        }
    __syncthreads();

    #pragma unroll
    for (int ks = 0; ks < 4; ++ks) {
        const int kc = ks * 32 + (lane >> 4) * 8;
        bf16x8 sf[2], vf[4];
        #pragma unroll
        for (int mi = 0; mi < 2; ++mi) sf[mi] = *(const bf16x8*)&Ss[w * 32 + mi * 16 + (lane & 15)][kc];
        #pragma unroll
        for (int ni = 0; ni < 4; ++ni) {
            int d = ni * 16 + (lane & 15);
            vf[ni] = *(const bf16x8*)&VTs[d][kc ^ (((d >> 3) & 7) << 3)];
        }
        #pragma unroll
        for (int mi = 0; mi < 2; ++mi)
            #pragma unroll
            for (int ni = 0; ni < 4; ++ni)
                accO[mi][ni] = MFMA16(sf[mi], vf[ni], accO[mi][ni]);
    }

    #pragma unroll
    for (int mi = 0; mi < 2; ++mi)
        #pragma unroll
        for (int ni = 0; ni < 4; ++ni) {
            const int trow = t0 + w * 32 + mi * 16 + (lane >> 4) * 4;
            const int d = ni * 16 + (lane & 15);
            #pragma unroll
            for (int r = 0; r < 4; ++r)
                xo[(size_t)(b * 2048 + trow + r) * 1024 + h * 64 + d] = (bf16)accO[mi][ni][r];
        }
}

extern "C" void kernel_launch(void* const* d_in, const int* in_sizes, int n_in,
                              void* d_out, int out_size, void* d_ws, size_t ws_size,
                              hipStream_t stream) {
    const float* x  = (const float*)d_in[0];   // (2,2048,1024)
    const float* wq = (const float*)d_in[1];   // (3072,1024)
    const float* wo = (const float*)d_in[2];   // (1024,1024)

    char* ws = (char*)d_ws;
    bf16*  xbf  = (bf16*)(ws);
    float* Wc   = (float*)(ws);
    bf16*  xo   = (bf16*)(ws);
    bf16*  wqkv = (bf16*)(ws + (8u << 20));
    bf16*  Wpre = (bf16*)(ws + (8u << 20));
    bf16*  wout = (bf16*)(ws + (14u << 20));
    bf16*  qkv  = (bf16*)(ws + (16u << 20));   // 24MB
    float* part = (float*)(ws + (40u << 20));  // 256KB

    cvt3_k<<<4096, 256, 0, stream>>>(x, wq, wo, xbf, wqkv, wout);

    gemm256<bf16><<<dim3(12, 16), 512, 0, stream>>>(xbf, wqkv, qkv, 4096, 3072, 1024);

    qsA_k<<<512, 256, 0, stream>>>(qkv, part);
    scanB_k<<<1024, 64, 0, stream>>>(qkv, part);

    kvchunk_k<<<512, 256, 0, stream>>>(qkv, Wc);
    kvscan_k<<<512, 256, 0, stream>>>(Wc, Wpre);
    attn2_k<<<dim3(16, 32), 256, 0, stream>>>(qkv, Wpre, xo);

    gemm_nt<float><<<dim3(8, 32), 256, 0, stream>>>(xo, wout, (float*)d_out, 4096, 1024, 1024);
}

// Round 9
// 116.563 us; speedup vs baseline: 1.0762x; 1.0762x over previous
//
#include <hip/hip_runtime.h>

typedef __bf16 bf16;
typedef __bf16 bf16x8 __attribute__((ext_vector_type(8)));
typedef float  f32x4  __attribute__((ext_vector_type(4)));

#define MFMA16(a, b, c) __builtin_amdgcn_mfma_f32_16x16x32_bf16((a), (b), (c), 0, 0, 0)

#define GLOAD16(gp, lp) __builtin_amdgcn_global_load_lds( \
    (const __attribute__((address_space(1))) void*)(gp),  \
    (__attribute__((address_space(3))) void*)(lp), 16, 0, 0)

#define BAR __builtin_amdgcn_s_barrier()
#define WAITV0 asm volatile("s_waitcnt vmcnt(0)" ::: "memory")

// ==== unified 2-phase double-buffered NT GEMM ====
// C(MxN) = A(MxK) @ B(NxK)^T; BK=64; 3-bit XOR LDS swizzle; XCD block swizzle;
// per K-tile: stage(next) -> read all frags -> MFMA -> vmcnt(0) -> 1 barrier.
template <typename CT, int BM, int BN, int WM, int WN>
__global__ __launch_bounds__(WM * WN * 64, 1) void gemm2ph(const bf16* __restrict__ A,
                                                           const bf16* __restrict__ B,
                                                           CT* __restrict__ C,
                                                           int M, int N, int K) {
    constexpr int THREADS = WM * WN * 64;
    constexpr int MI = BM / WM / 16, NI = BN / WN / 16;
    constexpr int LA = BM * 8 / THREADS, LB = BN * 8 / THREADS;
    __shared__ bf16 sA[2][BM * 64];
    __shared__ bf16 sB[2][BN * 64];
    const int tid = threadIdx.x, lane = tid & 63, w = tid >> 6;
    const int wm = w / WN, wn = w % WN;

    // XCD-aware bijective block swizzle (nwg % 8 == 0)
    const int nwg = gridDim.x * gridDim.y;
    const int lin = blockIdx.y * gridDim.x + blockIdx.x;
    const int cpx = nwg >> 3;
    const int swzb = (lin & 7) * cpx + (lin >> 3);
    const int row0 = (swzb / gridDim.x) * BM, col0 = (swzb % gridDim.x) * BN;
    const int nt = K >> 6;

    // 3-bit row-XOR swizzle: LDS[r][c] holds global[r][c ^ (r&7)*8]
    const int sw3   = (lane & 7) * 8;
    const int s0k   = (lane >> 4) * 8;
    const int koff0 = s0k ^ sw3;
    const int koff1 = (s0k | 32) ^ sw3;
    const int aoff  = (wm * (BM / WM) + (lane & 15)) * 64;
    const int boff  = (wn * (BN / WN) + (lane & 15)) * 64;

    auto stage = [&](int slot, int t) {
        #pragma unroll
        for (int i = 0; i < LA; ++i) {
            int c = i * THREADS + tid; int r = c >> 3;
            int c8 = ((c & 7) * 8) ^ ((r & 7) * 8);
            GLOAD16(A + (size_t)(row0 + r) * K + t * 64 + c8, &sA[slot][c * 8]);
        }
        #pragma unroll
        for (int i = 0; i < LB; ++i) {
            int c = i * THREADS + tid; int r = c >> 3;
            int c8 = ((c & 7) * 8) ^ ((r & 7) * 8);
            GLOAD16(B + (size_t)(col0 + r) * K + t * 64 + c8, &sB[slot][c * 8]);
        }
    };

    f32x4 acc[MI][NI] = {};

    stage(0, 0);
    WAITV0; BAR;

    for (int j = 0; j < nt; ++j) {
        const int s = j & 1;
        if (j + 1 < nt) stage(s ^ 1, j + 1);     // issue early, drain at tile end
        const bf16* sa = sA[s];
        const bf16* sb = sB[s];
        bf16x8 a[MI][2], b[NI][2];
        #pragma unroll
        for (int mi = 0; mi < MI; ++mi) {
            a[mi][0] = *(const bf16x8*)&sa[aoff + mi * 1024 + koff0];
            a[mi][1] = *(const bf16x8*)&sa[aoff + mi * 1024 + koff1];
        }
        #pragma unroll
        for (int ni = 0; ni < NI; ++ni) {
            b[ni][0] = *(const bf16x8*)&sb[boff + ni * 1024 + koff0];
            b[ni][1] = *(const bf16x8*)&sb[boff + ni * 1024 + koff1];
        }
        __builtin_amdgcn_s_setprio(1);
        #pragma unroll
        for (int mi = 0; mi < MI; ++mi)
            #pragma unroll
            for (int ni = 0; ni < NI; ++ni) {
                acc[mi][ni] = MFMA16(a[mi][0], b[ni][0], acc[mi][ni]);
                acc[mi][ni] = MFMA16(a[mi][1], b[ni][1], acc[mi][ni]);
            }
        __builtin_amdgcn_s_setprio(0);
        WAITV0;    // next tile fully landed (memory-clobber asm also fences reordering)
        BAR;
    }

    const int crow = row0 + wm * (BM / WM) + (lane >> 4) * 4;
    const int ccol = col0 + wn * (BN / WN) + (lane & 15);
    #pragma unroll
    for (int mi = 0; mi < MI; ++mi)
        #pragma unroll
        for (int ni = 0; ni < NI; ++ni)
            #pragma unroll
            for (int r = 0; r < 4; ++r)
                C[(size_t)(crow + mi * 16 + r) * N + ccol + ni * 16] = (CT)acc[mi][ni][r];
}

// ---------------- fused f32 -> bf16 bulk convert (x, W_qkv, W_out) ----------------
__global__ __launch_bounds__(256) void cvt3_k(const float* __restrict__ x,
                                              const float* __restrict__ wq,
                                              const float* __restrict__ wo,
                                              bf16* __restrict__ xbf,
                                              bf16* __restrict__ wqkv,
                                              bf16* __restrict__ wout) {
    int i = blockIdx.x * 256 + threadIdx.x;          // 0 .. 1048575
    const float* in; bf16* out; int off;
    if (i < 524288)       { in = x;  out = xbf;  off = i; }
    else if (i < 917504)  { in = wq; out = wqkv; off = i - 524288; }
    else                  { in = wo; out = wout; off = i - 917504; }
    f32x4 a = *(const f32x4*)(in + (size_t)off * 8);
    f32x4 b = *(const f32x4*)(in + (size_t)off * 8 + 4);
    bf16x8 o;
    o[0] = (bf16)a[0]; o[1] = (bf16)a[1]; o[2] = (bf16)a[2]; o[3] = (bf16)a[3];
    o[4] = (bf16)b[0]; o[5] = (bf16)b[1]; o[6] = (bf16)b[2]; o[7] = (bf16)b[3];
    *(bf16x8*)(out + (size_t)off * 8) = o;
}

// ---- fused: blocks 0-255 = q row-softmax; blocks 256-511 = exp(k) partial sums ----
__global__ __launch_bounds__(256) void qsA_k(bf16* __restrict__ qkv, float* __restrict__ part) {
    if (blockIdx.x < 256) {
        int tg = blockIdx.x * 256 + threadIdx.x;   // 0..65535
        int h = tg & 15, r = tg >> 4;
        bf16* q = qkv + (size_t)r * 3072 + h * 64;
        bf16x8 buf[8];
        float v[64];
        #pragma unroll
        for (int i = 0; i < 8; ++i) buf[i] = *(const bf16x8*)(q + i * 8);
        float m = -3.0e38f;
        #pragma unroll
        for (int i = 0; i < 8; ++i)
            #pragma unroll
            for (int e = 0; e < 8; ++e) { v[i * 8 + e] = (float)buf[i][e]; m = fmaxf(m, v[i * 8 + e]); }
        float s = 0.f;
        #pragma unroll
        for (int i = 0; i < 64; ++i) { v[i] = __expf(v[i] - m); s += v[i]; }
        float inv = 0.125f / s;
        #pragma unroll
        for (int i = 0; i < 8; ++i) {
            bf16x8 o;
            #pragma unroll
            for (int e = 0; e < 8; ++e) o[e] = (bf16)(v[i * 8 + e] * inv);
            *(bf16x8*)(q + i * 8) = o;
        }
    } else {
        int blk = (blockIdx.x - 256) * 4 + (threadIdx.x >> 6);   // 0..1023
        int bh = blk >> 5, seg = blk & 31;
        int b = bh >> 4, h = bh & 15;
        int c = threadIdx.x & 63;
        const bf16* kb = qkv + (size_t)b * 2048 * 3072 + 1024 + h * 64 + c;
        float s = 0.f;
        for (int t0 = seg * 64; t0 < seg * 64 + 64; t0 += 8) {
            float e[8];
            #pragma unroll
            for (int u = 0; u < 8; ++u) e[u] = (float)kb[(size_t)(t0 + u) * 3072];
            #pragma unroll
            for (int u = 0; u < 8; ++u) s += __expf(e[u]);
        }
        part[blk * 64 + c] = s;
    }
}

// -------- carry-in sweep: q -> qn = qsm/(kcum+eps), k -> exp(k), in place, 8-batched --------
__global__ __launch_bounds__(64) void scanB_k(bf16* __restrict__ qkv, const float* __restrict__ part) {
    int blk = blockIdx.x;
    int bh = blk >> 5, seg = blk & 31;
    int b = bh >> 4, h = bh & 15;
    int c = threadIdx.x;
    bf16* qb = qkv + (size_t)b * 2048 * 3072 + h * 64 + c;
    bf16* kb = qb + 1024;
    float run = 0.f;
    for (int i = 0; i < seg; ++i) run += part[(bh * 32 + i) * 64 + c];
    for (int t0 = seg * 64; t0 < seg * 64 + 64; t0 += 8) {
        float e[8], qv[8];
        #pragma unroll
        for (int u = 0; u < 8; ++u) e[u] = (float)kb[(size_t)(t0 + u) * 3072];
        #pragma unroll
        for (int u = 0; u < 8; ++u) qv[u] = (float)qb[(size_t)(t0 + u) * 3072];
        #pragma unroll
        for (int u = 0; u < 8; ++u) {
            e[u] = __expf(e[u]);
            run += e[u];
            qv[u] = qv[u] / (run + 1e-9f);
        }
        #pragma unroll
        for (int u = 0; u < 8; ++u) {
            qb[(size_t)(t0 + u) * 3072] = (bf16)qv[u];
            kb[(size_t)(t0 + u) * 3072] = (bf16)e[u];
        }
    }
}

// -------- phase 1: per-chunk KV state  Wc[d][c] = sum_s V[s,d]*kexp[s,c]  (f32) --------
__global__ __launch_bounds__(256) void kvchunk_k(const bf16* __restrict__ qkv, float* __restrict__ Wc) {
    __shared__ bf16 KT[64][136];
    __shared__ bf16 VT[64][136];
    const int blk = blockIdx.x, bh = blk >> 4, j = blk & 15;
    const int b = bh >> 4, h = bh & 15;
    const int tid = threadIdx.x, lane = tid & 63, w = tid >> 6;
    const bf16* kbase = qkv + (size_t)(b * 2048 + j * 128) * 3072 + 1024 + h * 64;
    const bf16* vbase = kbase + 1024;

    #pragma unroll
    for (int i = 0; i < 4; ++i) {
        int idx = i * 256 + tid;
        int s = idx >> 3, cg = (idx & 7) * 8;
        bf16x8 k8 = *(const bf16x8*)(kbase + (size_t)s * 3072 + cg);
        bf16x8 v8 = *(const bf16x8*)(vbase + (size_t)s * 3072 + cg);
        #pragma unroll
        for (int e = 0; e < 8; ++e) {
            int d = cg + e;
            int sw2 = s ^ (((d >> 3) & 7) << 3);
            KT[d][sw2] = k8[e];
            VT[d][sw2] = v8[e];
        }
    }
    __syncthreads();

    f32x4 acc[4] = {};
    const int dr = w * 16 + (lane & 15);
    const int swd = ((dr >> 3) & 7) << 3;
    #pragma unroll
    for (int ks = 0; ks < 4; ++ks) {
        const int sc = ks * 32 + (lane >> 4) * 8;
        bf16x8 av = *(const bf16x8*)&VT[dr][sc ^ swd];
        #pragma unroll
        for (int ni = 0; ni < 4; ++ni) {
            int cr = ni * 16 + (lane & 15);
            bf16x8 bk = *(const bf16x8*)&KT[cr][sc ^ (((cr >> 3) & 7) << 3)];
            acc[ni] = MFMA16(av, bk, acc[ni]);
        }
    }
    float* out = Wc + (size_t)blk * 4096;
    const int dw = w * 16 + (lane >> 4) * 4;
    #pragma unroll
    for (int ni = 0; ni < 4; ++ni)
        #pragma unroll
        for (int r = 0; r < 4; ++r)
            out[(dw + r) * 64 + ni * 16 + (lane & 15)] = acc[ni][r];
}

// -------- phase 2: exclusive cumsum of chunk states across 16 chunks, f32 -> bf16 --------
__global__ __launch_bounds__(256) void kvscan_k(const float* __restrict__ Wc, bf16* __restrict__ Wpre) {
    int e = blockIdx.x * 256 + threadIdx.x;     // 131072
    int bh = e >> 12, off = e & 4095;
    float run = 0.f;
    #pragma unroll
    for (int j = 0; j < 16; ++j) {
        size_t idx = (size_t)(bh * 16 + j) * 4096 + off;
        Wpre[idx] = (bf16)run;
        run += Wc[idx];
    }
}

// -------- phase 3: O = qn @ Wpre (far) + masked (qn@K^T) @ V (near), causal wave-skip --------
__global__ __launch_bounds__(256) void attn2_k(const bf16* __restrict__ qkv,
                                               const bf16* __restrict__ Wpre,
                                               bf16* __restrict__ xo) {
    __shared__ bf16 Ks[128][72];
    __shared__ bf16 VTs[64][136];
    __shared__ bf16 Ss[128][136];
    const int bh = blockIdx.y, b = bh >> 4, h = bh & 15;
    const int ti = blockIdx.x, t0 = ti * 128;
    const int tid = threadIdx.x, lane = tid & 63, w = tid >> 6;
    const bf16* qn = qkv + (size_t)b * 2048 * 3072 + h * 64;
    const bf16* ke = qn + 1024;
    const bf16* vv = qn + 2048;

    bf16x8 qf[2][2];
    #pragma unroll
    for (int mi = 0; mi < 2; ++mi)
        #pragma unroll
        for (int kk = 0; kk < 2; ++kk)
            qf[mi][kk] = *(const bf16x8*)(qn + (size_t)(t0 + w * 32 + mi * 16 + (lane & 15)) * 3072
                                          + kk * 32 + (lane >> 4) * 8);
    const bf16* wp = Wpre + (size_t)(bh * 16 + ti) * 4096;
    bf16x8 wf[4][2];
    #pragma unroll
    for (int ni = 0; ni < 4; ++ni)
        #pragma unroll
        for (int kk = 0; kk < 2; ++kk)
            wf[ni][kk] = *(const bf16x8*)(wp + (ni * 16 + (lane & 15)) * 64 + kk * 32 + (lane >> 4) * 8);

    #pragma unroll
    for (int i = 0; i < 4; ++i) {
        int idx = i * 256 + tid;
        int s = idx >> 3, cg = (idx & 7) * 8;
        *(f32x4*)&Ks[s][cg] = *(const f32x4*)(ke + (size_t)(t0 + s) * 3072 + cg);
        bf16x8 v8 = *(const bf16x8*)(vv + (size_t)(t0 + s) * 3072 + cg);
        #pragma unroll
        for (int e = 0; e < 8; ++e) {
            int d = cg + e;
            VTs[d][s ^ (((d >> 3) & 7) << 3)] = v8[e];
        }
    }
    __syncthreads();

    // far field
    f32x4 accO[2][4] = {};
    #pragma unroll
    for (int kk = 0; kk < 2; ++kk)
        #pragma unroll
        for (int mi = 0; mi < 2; ++mi)
            #pragma unroll
            for (int ni = 0; ni < 4; ++ni)
                accO[mi][ni] = MFMA16(qf[mi][kk], wf[ni][kk], accO[mi][ni]);

    // near: S = qn @ K^T — wave w needs only s-cols < 32*(w+1)  (wave-uniform skip)
    const int nq = 2 * (w + 1);
    f32x4 accS[2][8] = {};
    #pragma unroll
    for (int kk = 0; kk < 2; ++kk) {
        const int kc = kk * 32 + (lane >> 4) * 8;
        bf16x8 kf[8];
        #pragma unroll
        for (int ni = 0; ni < 8; ++ni)
            if (ni < nq) kf[ni] = *(const bf16x8*)&Ks[ni * 16 + (lane & 15)][kc];
        #pragma unroll
        for (int mi = 0; mi < 2; ++mi)
            #pragma unroll
            for (int ni = 0; ni < 8; ++ni)
                if (ni < nq) accS[mi][ni] = MFMA16(qf[mi][kk], kf[ni], accS[mi][ni]);
    }
    #pragma unroll
    for (int mi = 0; mi < 2; ++mi)
        #pragma unroll
        for (int ni = 0; ni < 8; ++ni)
            if (ni < nq) {
                const int tb = w * 32 + mi * 16 + (lane >> 4) * 4;
                const int sb = ni * 16 + (lane & 15);
                #pragma unroll
                for (int r = 0; r < 4; ++r) {
                    float sv = accS[mi][ni][r];
                    if (sb > tb + r) sv = 0.f;
                    Ss[tb + r][sb] = (bf16)sv;
                }
            }
    // no __syncthreads: Ss rows are wave-private (written and read by the same wave)

    // O += S @ V — wave w needs only k-steps <= w
    #pragma unroll
    for (int ks = 0; ks < 4; ++ks)
        if (ks <= w) {
            const int kc = ks * 32 + (lane >> 4) * 8;
            bf16x8 sf[2], vf[4];
            #pragma unroll
            for (int mi = 0; mi < 2; ++mi) sf[mi] = *(const bf16x8*)&Ss[w * 32 + mi * 16 + (lane & 15)][kc];
            #pragma unroll
            for (int ni = 0; ni < 4; ++ni) {
                int d = ni * 16 + (lane & 15);
                vf[ni] = *(const bf16x8*)&VTs[d][kc ^ (((d >> 3) & 7) << 3)];
            }
            #pragma unroll
            for (int mi = 0; mi < 2; ++mi)
                #pragma unroll
                for (int ni = 0; ni < 4; ++ni)
                    accO[mi][ni] = MFMA16(sf[mi], vf[ni], accO[mi][ni]);
        }

    #pragma unroll
    for (int mi = 0; mi < 2; ++mi)
        #pragma unroll
        for (int ni = 0; ni < 4; ++ni) {
            const int trow = t0 + w * 32 + mi * 16 + (lane >> 4) * 4;
            const int d = ni * 16 + (lane & 15);
            #pragma unroll
            for (int r = 0; r < 4; ++r)
                xo[(size_t)(b * 2048 + trow + r) * 1024 + h * 64 + d] = (bf16)accO[mi][ni][r];
        }
}

extern "C" void kernel_launch(void* const* d_in, const int* in_sizes, int n_in,
                              void* d_out, int out_size, void* d_ws, size_t ws_size,
                              hipStream_t stream) {
    const float* x  = (const float*)d_in[0];   // (2,2048,1024)
    const float* wq = (const float*)d_in[1];   // (3072,1024)
    const float* wo = (const float*)d_in[2];   // (1024,1024)

    char* ws = (char*)d_ws;
    bf16*  xbf  = (bf16*)(ws);
    float* Wc   = (float*)(ws);
    bf16*  xo   = (bf16*)(ws);
    bf16*  wqkv = (bf16*)(ws + (8u << 20));
    bf16*  Wpre = (bf16*)(ws + (8u << 20));
    bf16*  wout = (bf16*)(ws + (14u << 20));
    bf16*  qkv  = (bf16*)(ws + (16u << 20));   // 24MB
    float* part = (float*)(ws + (40u << 20));  // 256KB

    cvt3_k<<<4096, 256, 0, stream>>>(x, wq, wo, xbf, wqkv, wout);

    gemm2ph<bf16, 256, 256, 2, 4><<<dim3(12, 16), 512, 0, stream>>>(xbf, wqkv, qkv, 4096, 3072, 1024);

    qsA_k<<<512, 256, 0, stream>>>(qkv, part);
    scanB_k<<<1024, 64, 0, stream>>>(qkv, part);

    kvchunk_k<<<512, 256, 0, stream>>>(qkv, Wc);
    kvscan_k<<<512, 256, 0, stream>>>(Wc, Wpre);
    attn2_k<<<dim3(16, 32), 256, 0, stream>>>(qkv, Wpre, xo);

    gemm2ph<float, 128, 64, 2, 2><<<dim3(16, 32), 256, 0, stream>>>(xo, wout, (float*)d_out, 4096, 1024, 1024);
}

// Round 10
// 111.445 us; speedup vs baseline: 1.1256x; 1.0459x over previous
//
#include <hip/hip_runtime.h>

typedef __bf16 bf16;
typedef __bf16 bf16x8 __attribute__((ext_vector_type(8)));
typedef float  f32x4  __attribute__((ext_vector_type(4)));

#define MFMA16(a, b, c) __builtin_amdgcn_mfma_f32_16x16x32_bf16((a), (b), (c), 0, 0, 0)

#define GLOAD16(gp, lp) __builtin_amdgcn_global_load_lds( \
    (const __attribute__((address_space(1))) void*)(gp),  \
    (__attribute__((address_space(3))) void*)(lp), 16, 0, 0)

#define BAR __builtin_amdgcn_s_barrier()
#define WAITV0 asm volatile("s_waitcnt vmcnt(0)" ::: "memory")

// ==== unified 2-phase double-buffered NT GEMM ====
// C(MxN) = A(MxK) @ B(NxK)^T; BK=64; 3-bit XOR LDS swizzle; XCD block swizzle;
// per K-tile: stage(next) -> read all frags -> MFMA -> vmcnt(0) -> 1 barrier.
template <typename CT, int BM, int BN, int WM, int WN>
__global__ __launch_bounds__(WM * WN * 64, 1) void gemm2ph(const bf16* __restrict__ A,
                                                           const bf16* __restrict__ B,
                                                           CT* __restrict__ C,
                                                           int M, int N, int K) {
    constexpr int THREADS = WM * WN * 64;
    constexpr int MI = BM / WM / 16, NI = BN / WN / 16;
    constexpr int LA = BM * 8 / THREADS, LB = BN * 8 / THREADS;
    __shared__ bf16 sA[2][BM * 64];
    __shared__ bf16 sB[2][BN * 64];
    const int tid = threadIdx.x, lane = tid & 63, w = tid >> 6;
    const int wm = w / WN, wn = w % WN;

    // XCD-aware bijective block swizzle (nwg % 8 == 0)
    const int nwg = gridDim.x * gridDim.y;
    const int lin = blockIdx.y * gridDim.x + blockIdx.x;
    const int cpx = nwg >> 3;
    const int swzb = (lin & 7) * cpx + (lin >> 3);
    const int row0 = (swzb / gridDim.x) * BM, col0 = (swzb % gridDim.x) * BN;
    const int nt = K >> 6;

    // 3-bit row-XOR swizzle: LDS[r][c] holds global[r][c ^ (r&7)*8]
    const int sw3   = (lane & 7) * 8;
    const int s0k   = (lane >> 4) * 8;
    const int koff0 = s0k ^ sw3;
    const int koff1 = (s0k | 32) ^ sw3;
    const int aoff  = (wm * (BM / WM) + (lane & 15)) * 64;
    const int boff  = (wn * (BN / WN) + (lane & 15)) * 64;

    auto stage = [&](int slot, int t) {
        #pragma unroll
        for (int i = 0; i < LA; ++i) {
            int c = i * THREADS + tid; int r = c >> 3;
            int c8 = ((c & 7) * 8) ^ ((r & 7) * 8);
            GLOAD16(A + (size_t)(row0 + r) * K + t * 64 + c8, &sA[slot][c * 8]);
        }
        #pragma unroll
        for (int i = 0; i < LB; ++i) {
            int c = i * THREADS + tid; int r = c >> 3;
            int c8 = ((c & 7) * 8) ^ ((r & 7) * 8);
            GLOAD16(B + (size_t)(col0 + r) * K + t * 64 + c8, &sB[slot][c * 8]);
        }
    };

    f32x4 acc[MI][NI] = {};

    stage(0, 0);
    WAITV0; BAR;

    for (int j = 0; j < nt; ++j) {
        const int s = j & 1;
        if (j + 1 < nt) stage(s ^ 1, j + 1);     // issue early, drain at tile end
        const bf16* sa = sA[s];
        const bf16* sb = sB[s];
        bf16x8 a[MI][2], b[NI][2];
        #pragma unroll
        for (int mi = 0; mi < MI; ++mi) {
            a[mi][0] = *(const bf16x8*)&sa[aoff + mi * 1024 + koff0];
            a[mi][1] = *(const bf16x8*)&sa[aoff + mi * 1024 + koff1];
        }
        #pragma unroll
        for (int ni = 0; ni < NI; ++ni) {
            b[ni][0] = *(const bf16x8*)&sb[boff + ni * 1024 + koff0];
            b[ni][1] = *(const bf16x8*)&sb[boff + ni * 1024 + koff1];
        }
        __builtin_amdgcn_s_setprio(1);
        #pragma unroll
        for (int mi = 0; mi < MI; ++mi)
            #pragma unroll
            for (int ni = 0; ni < NI; ++ni) {
                acc[mi][ni] = MFMA16(a[mi][0], b[ni][0], acc[mi][ni]);
                acc[mi][ni] = MFMA16(a[mi][1], b[ni][1], acc[mi][ni]);
            }
        __builtin_amdgcn_s_setprio(0);
        WAITV0;    // next tile fully landed (memory-clobber asm also fences reordering)
        BAR;
    }

    const int crow = row0 + wm * (BM / WM) + (lane >> 4) * 4;
    const int ccol = col0 + wn * (BN / WN) + (lane & 15);
    #pragma unroll
    for (int mi = 0; mi < MI; ++mi)
        #pragma unroll
        for (int ni = 0; ni < NI; ++ni)
            #pragma unroll
            for (int r = 0; r < 4; ++r)
                C[(size_t)(crow + mi * 16 + r) * N + ccol + ni * 16] = (CT)acc[mi][ni][r];
}

// ---------------- fused f32 -> bf16 bulk convert, 16 elems/thread ----------------
__global__ __launch_bounds__(256) void cvt3_k(const float* __restrict__ x,
                                              const float* __restrict__ wq,
                                              const float* __restrict__ wo,
                                              bf16* __restrict__ xbf,
                                              bf16* __restrict__ wqkv,
                                              bf16* __restrict__ wout) {
    int i = blockIdx.x * 256 + threadIdx.x;          // 0 .. 524287 chunks of 16
    const float* in; bf16* out; int off;
    if (i < 262144)       { in = x;  out = xbf;  off = i; }
    else if (i < 458752)  { in = wq; out = wqkv; off = i - 262144; }
    else                  { in = wo; out = wout; off = i - 458752; }
    const float* p = in + (size_t)off * 16;
    #pragma unroll
    for (int half = 0; half < 2; ++half) {
        f32x4 a = *(const f32x4*)(p + half * 8);
        f32x4 b = *(const f32x4*)(p + half * 8 + 4);
        bf16x8 o;
        o[0] = (bf16)a[0]; o[1] = (bf16)a[1]; o[2] = (bf16)a[2]; o[3] = (bf16)a[3];
        o[4] = (bf16)b[0]; o[5] = (bf16)b[1]; o[6] = (bf16)b[2]; o[7] = (bf16)b[3];
        *(bf16x8*)(out + (size_t)off * 16 + half * 8) = o;
    }
}

// ---- fused: blocks 0-255 = q row-softmax; blocks 256-511 = exp(k) partial sums ----
__global__ __launch_bounds__(256) void qsA_k(bf16* __restrict__ qkv, float* __restrict__ part) {
    if (blockIdx.x < 256) {
        int tg = blockIdx.x * 256 + threadIdx.x;   // 0..65535
        int h = tg & 15, r = tg >> 4;
        bf16* q = qkv + (size_t)r * 3072 + h * 64;
        bf16x8 buf[8];
        float v[64];
        #pragma unroll
        for (int i = 0; i < 8; ++i) buf[i] = *(const bf16x8*)(q + i * 8);
        float m = -3.0e38f;
        #pragma unroll
        for (int i = 0; i < 8; ++i)
            #pragma unroll
            for (int e = 0; e < 8; ++e) { v[i * 8 + e] = (float)buf[i][e]; m = fmaxf(m, v[i * 8 + e]); }
        float s = 0.f;
        #pragma unroll
        for (int i = 0; i < 64; ++i) { v[i] = __expf(v[i] - m); s += v[i]; }
        float inv = 0.125f / s;
        #pragma unroll
        for (int i = 0; i < 8; ++i) {
            bf16x8 o;
            #pragma unroll
            for (int e = 0; e < 8; ++e) o[e] = (bf16)(v[i * 8 + e] * inv);
            *(bf16x8*)(q + i * 8) = o;
        }
    } else {
        int blk = (blockIdx.x - 256) * 4 + (threadIdx.x >> 6);   // 0..1023
        int bh = blk >> 5, seg = blk & 31;
        int b = bh >> 4, h = bh & 15;
        int c = threadIdx.x & 63;
        const bf16* kb = qkv + (size_t)b * 2048 * 3072 + 1024 + h * 64 + c;
        float s = 0.f;
        for (int t0 = seg * 64; t0 < seg * 64 + 64; t0 += 8) {
            float e[8];
            #pragma unroll
            for (int u = 0; u < 8; ++u) e[u] = (float)kb[(size_t)(t0 + u) * 3072];
            #pragma unroll
            for (int u = 0; u < 8; ++u) s += __expf(e[u]);
        }
        part[blk * 64 + c] = s;
    }
}

// -------- carry-in sweep: q -> qn = qsm/(kcum+eps), k -> exp(k), in place, 8-batched --------
__global__ __launch_bounds__(64) void scanB_k(bf16* __restrict__ qkv, const float* __restrict__ part) {
    int blk = blockIdx.x;
    int bh = blk >> 5, seg = blk & 31;
    int b = bh >> 4, h = bh & 15;
    int c = threadIdx.x;
    bf16* qb = qkv + (size_t)b * 2048 * 3072 + h * 64 + c;
    bf16* kb = qb + 1024;
    float run = 0.f;
    for (int i = 0; i < seg; ++i) run += part[(bh * 32 + i) * 64 + c];
    for (int t0 = seg * 64; t0 < seg * 64 + 64; t0 += 8) {
        float e[8], qv[8];
        #pragma unroll
        for (int u = 0; u < 8; ++u) e[u] = (float)kb[(size_t)(t0 + u) * 3072];
        #pragma unroll
        for (int u = 0; u < 8; ++u) qv[u] = (float)qb[(size_t)(t0 + u) * 3072];
        #pragma unroll
        for (int u = 0; u < 8; ++u) {
            e[u] = __expf(e[u]);
            run += e[u];
            qv[u] = qv[u] / (run + 1e-9f);
        }
        #pragma unroll
        for (int u = 0; u < 8; ++u) {
            qb[(size_t)(t0 + u) * 3072] = (bf16)qv[u];
            kb[(size_t)(t0 + u) * 3072] = (bf16)e[u];
        }
    }
}

// -------- phase 1: per-chunk KV state  Wc[d][c] = sum_s V[s,d]*kexp[s,c]  (f32) --------
__global__ __launch_bounds__(256) void kvchunk_k(const bf16* __restrict__ qkv, float* __restrict__ Wc) {
    __shared__ bf16 KT[64][136];
    __shared__ bf16 VT[64][136];
    const int blk = blockIdx.x, bh = blk >> 4, j = blk & 15;
    const int b = bh >> 4, h = bh & 15;
    const int tid = threadIdx.x, lane = tid & 63, w = tid >> 6;
    const bf16* kbase = qkv + (size_t)(b * 2048 + j * 128) * 3072 + 1024 + h * 64;
    const bf16* vbase = kbase + 1024;

    #pragma unroll
    for (int i = 0; i < 4; ++i) {
        int idx = i * 256 + tid;
        int s = idx >> 3, cg = (idx & 7) * 8;
        bf16x8 k8 = *(const bf16x8*)(kbase + (size_t)s * 3072 + cg);
        bf16x8 v8 = *(const bf16x8*)(vbase + (size_t)s * 3072 + cg);
        #pragma unroll
        for (int e = 0; e < 8; ++e) {
            int d = cg + e;
            int sw2 = s ^ (((d >> 3) & 7) << 3);
            KT[d][sw2] = k8[e];
            VT[d][sw2] = v8[e];
        }
    }
    __syncthreads();

    f32x4 acc[4] = {};
    const int dr = w * 16 + (lane & 15);
    const int swd = ((dr >> 3) & 7) << 3;
    #pragma unroll
    for (int ks = 0; ks < 4; ++ks) {
        const int sc = ks * 32 + (lane >> 4) * 8;
        bf16x8 av = *(const bf16x8*)&VT[dr][sc ^ swd];
        #pragma unroll
        for (int ni = 0; ni < 4; ++ni) {
            int cr = ni * 16 + (lane & 15);
            bf16x8 bk = *(const bf16x8*)&KT[cr][sc ^ (((cr >> 3) & 7) << 3)];
            acc[ni] = MFMA16(av, bk, acc[ni]);
        }
    }
    float* out = Wc + (size_t)blk * 4096;
    const int dw = w * 16 + (lane >> 4) * 4;
    #pragma unroll
    for (int ni = 0; ni < 4; ++ni)
        #pragma unroll
        for (int r = 0; r < 4; ++r)
            out[(dw + r) * 64 + ni * 16 + (lane & 15)] = acc[ni][r];
}

// -------- phase 2: exclusive cumsum of chunk states across 16 chunks, f32 -> bf16 --------
__global__ __launch_bounds__(256) void kvscan_k(const float* __restrict__ Wc, bf16* __restrict__ Wpre) {
    int e = blockIdx.x * 256 + threadIdx.x;     // 131072
    int bh = e >> 12, off = e & 4095;
    float run = 0.f;
    #pragma unroll
    for (int j = 0; j < 16; ++j) {
        size_t idx = (size_t)(bh * 16 + j) * 4096 + off;
        Wpre[idx] = (bf16)run;
        run += Wc[idx];
    }
}

// -------- phase 3: O = qn @ Wpre (far) + masked (qn@K^T) @ V (near), causal wave-skip --------
__global__ __launch_bounds__(256) void attn2_k(const bf16* __restrict__ qkv,
                                               const bf16* __restrict__ Wpre,
                                               bf16* __restrict__ xo) {
    __shared__ bf16 Ks[128][72];
    __shared__ bf16 VTs[64][136];
    __shared__ bf16 Ss[128][136];
    const int bh = blockIdx.y, b = bh >> 4, h = bh & 15;
    const int ti = blockIdx.x, t0 = ti * 128;
    const int tid = threadIdx.x, lane = tid & 63, w = tid >> 6;
    const bf16* qn = qkv + (size_t)b * 2048 * 3072 + h * 64;
    const bf16* ke = qn + 1024;
    const bf16* vv = qn + 2048;

    bf16x8 qf[2][2];
    #pragma unroll
    for (int mi = 0; mi < 2; ++mi)
        #pragma unroll
        for (int kk = 0; kk < 2; ++kk)
            qf[mi][kk] = *(const bf16x8*)(qn + (size_t)(t0 + w * 32 + mi * 16 + (lane & 15)) * 3072
                                          + kk * 32 + (lane >> 4) * 8);
    const bf16* wp = Wpre + (size_t)(bh * 16 + ti) * 4096;
    bf16x8 wf[4][2];
    #pragma unroll
    for (int ni = 0; ni < 4; ++ni)
        #pragma unroll
        for (int kk = 0; kk < 2; ++kk)
            wf[ni][kk] = *(const bf16x8*)(wp + (ni * 16 + (lane & 15)) * 64 + kk * 32 + (lane >> 4) * 8);

    #pragma unroll
    for (int i = 0; i < 4; ++i) {
        int idx = i * 256 + tid;
        int s = idx >> 3, cg = (idx & 7) * 8;
        *(f32x4*)&Ks[s][cg] = *(const f32x4*)(ke + (size_t)(t0 + s) * 3072 + cg);
        bf16x8 v8 = *(const bf16x8*)(vv + (size_t)(t0 + s) * 3072 + cg);
        #pragma unroll
        for (int e = 0; e < 8; ++e) {
            int d = cg + e;
            VTs[d][s ^ (((d >> 3) & 7) << 3)] = v8[e];
        }
    }
    __syncthreads();

    // far field
    f32x4 accO[2][4] = {};
    #pragma unroll
    for (int kk = 0; kk < 2; ++kk)
        #pragma unroll
        for (int mi = 0; mi < 2; ++mi)
            #pragma unroll
            for (int ni = 0; ni < 4; ++ni)
                accO[mi][ni] = MFMA16(qf[mi][kk], wf[ni][kk], accO[mi][ni]);

    // near: S = qn @ K^T — wave w needs only s-cols < 32*(w+1)  (wave-uniform skip)
    const int nq = 2 * (w + 1);
    f32x4 accS[2][8] = {};
    #pragma unroll
    for (int kk = 0; kk < 2; ++kk) {
        const int kc = kk * 32 + (lane >> 4) * 8;
        bf16x8 kf[8];
        #pragma unroll
        for (int ni = 0; ni < 8; ++ni)
            if (ni < nq) kf[ni] = *(const bf16x8*)&Ks[ni * 16 + (lane & 15)][kc];
        #pragma unroll
        for (int mi = 0; mi < 2; ++mi)
            #pragma unroll
            for (int ni = 0; ni < 8; ++ni)
                if (ni < nq) accS[mi][ni] = MFMA16(qf[mi][kk], kf[ni], accS[mi][ni]);
    }
    #pragma unroll
    for (int mi = 0; mi < 2; ++mi)
        #pragma unroll
        for (int ni = 0; ni < 8; ++ni)
            if (ni < nq) {
                const int tb = w * 32 + mi * 16 + (lane >> 4) * 4;
                const int sb = ni * 16 + (lane & 15);
                #pragma unroll
                for (int r = 0; r < 4; ++r) {
                    float sv = accS[mi][ni][r];
                    if (sb > tb + r) sv = 0.f;
                    Ss[tb + r][sb] = (bf16)sv;
                }
            }
    // no __syncthreads: Ss rows are wave-private (written and read by the same wave)

    // O += S @ V — wave w needs only k-steps <= w
    #pragma unroll
    for (int ks = 0; ks < 4; ++ks)
        if (ks <= w) {
            const int kc = ks * 32 + (lane >> 4) * 8;
            bf16x8 sf[2], vf[4];
            #pragma unroll
            for (int mi = 0; mi < 2; ++mi) sf[mi] = *(const bf16x8*)&Ss[w * 32 + mi * 16 + (lane & 15)][kc];
            #pragma unroll
            for (int ni = 0; ni < 4; ++ni) {
                int d = ni * 16 + (lane & 15);
                vf[ni] = *(const bf16x8*)&VTs[d][kc ^ (((d >> 3) & 7) << 3)];
            }
            #pragma unroll
            for (int mi = 0; mi < 2; ++mi)
                #pragma unroll
                for (int ni = 0; ni < 4; ++ni)
                    accO[mi][ni] = MFMA16(sf[mi], vf[ni], accO[mi][ni]);
        }

    #pragma unroll
    for (int mi = 0; mi < 2; ++mi)
        #pragma unroll
        for (int ni = 0; ni < 4; ++ni) {
            const int trow = t0 + w * 32 + mi * 16 + (lane >> 4) * 4;
            const int d = ni * 16 + (lane & 15);
            #pragma unroll
            for (int r = 0; r < 4; ++r)
                xo[(size_t)(b * 2048 + trow + r) * 1024 + h * 64 + d] = (bf16)accO[mi][ni][r];
        }
}

extern "C" void kernel_launch(void* const* d_in, const int* in_sizes, int n_in,
                              void* d_out, int out_size, void* d_ws, size_t ws_size,
                              hipStream_t stream) {
    const float* x  = (const float*)d_in[0];   // (2,2048,1024)
    const float* wq = (const float*)d_in[1];   // (3072,1024)
    const float* wo = (const float*)d_in[2];   // (1024,1024)

    char* ws = (char*)d_ws;
    bf16*  xbf  = (bf16*)(ws);
    float* Wc   = (float*)(ws);
    bf16*  xo   = (bf16*)(ws);
    bf16*  wqkv = (bf16*)(ws + (8u << 20));
    bf16*  Wpre = (bf16*)(ws + (8u << 20));
    bf16*  wout = (bf16*)(ws + (14u << 20));
    bf16*  qkv  = (bf16*)(ws + (16u << 20));   // 24MB
    float* part = (float*)(ws + (40u << 20));  // 256KB

    cvt3_k<<<2048, 256, 0, stream>>>(x, wq, wo, xbf, wqkv, wout);

    // 256x192 tile -> grid 16x16 = 256 blocks = 1 block/CU on all 256 CUs
    gemm2ph<bf16, 256, 192, 2, 4><<<dim3(16, 16), 512, 0, stream>>>(xbf, wqkv, qkv, 4096, 3072, 1024);

    qsA_k<<<512, 256, 0, stream>>>(qkv, part);
    scanB_k<<<1024, 64, 0, stream>>>(qkv, part);

    kvchunk_k<<<512, 256, 0, stream>>>(qkv, Wc);
    kvscan_k<<<512, 256, 0, stream>>>(Wc, Wpre);
    attn2_k<<<dim3(16, 32), 256, 0, stream>>>(qkv, Wpre, xo);

    gemm2ph<float, 128, 64, 2, 2><<<dim3(16, 32), 256, 0, stream>>>(xo, wout, (float*)d_out, 4096, 1024, 1024);
}

// Round 11
// 108.323 us; speedup vs baseline: 1.1580x; 1.0288x over previous
//
#include <hip/hip_runtime.h>

typedef __bf16 bf16;
typedef __bf16 bf16x8 __attribute__((ext_vector_type(8)));
typedef float  f32x4  __attribute__((ext_vector_type(4)));

#define MFMA16(a, b, c) __builtin_amdgcn_mfma_f32_16x16x32_bf16((a), (b), (c), 0, 0, 0)

#define GLOAD16(gp, lp) __builtin_amdgcn_global_load_lds( \
    (const __attribute__((address_space(1))) void*)(gp),  \
    (__attribute__((address_space(3))) void*)(lp), 16, 0, 0)

#define BAR __builtin_amdgcn_s_barrier()
#define WAITV0 asm volatile("s_waitcnt vmcnt(0)" ::: "memory")

// ==== unified 2-phase double-buffered NT GEMM ====
// C(MxN) = A(MxK) @ B(NxK)^T; BK=64; 3-bit XOR LDS swizzle; XCD block swizzle;
// per K-tile: stage(next) -> read all frags -> MFMA -> vmcnt(0) -> 1 barrier.
// MINW = min waves/SIMD to declare (caps VGPR for multi-block residency).
template <typename CT, int BM, int BN, int WM, int WN, int MINW>
__global__ __launch_bounds__(WM * WN * 64, MINW) void gemm2ph(const bf16* __restrict__ A,
                                                              const bf16* __restrict__ B,
                                                              CT* __restrict__ C,
                                                              int M, int N, int K) {
    constexpr int THREADS = WM * WN * 64;
    constexpr int MI = BM / WM / 16, NI = BN / WN / 16;
    constexpr int LA = BM * 8 / THREADS, LB = BN * 8 / THREADS;
    __shared__ bf16 sA[2][BM * 64];
    __shared__ bf16 sB[2][BN * 64];
    const int tid = threadIdx.x, lane = tid & 63, w = tid >> 6;
    const int wm = w / WN, wn = w % WN;

    // XCD-aware bijective block swizzle (nwg % 8 == 0)
    const int nwg = gridDim.x * gridDim.y;
    const int lin = blockIdx.y * gridDim.x + blockIdx.x;
    const int cpx = nwg >> 3;
    const int swzb = (lin & 7) * cpx + (lin >> 3);
    const int row0 = (swzb / gridDim.x) * BM, col0 = (swzb % gridDim.x) * BN;
    const int nt = K >> 6;

    // 3-bit row-XOR swizzle: LDS[r][c] holds global[r][c ^ (r&7)*8]
    const int sw3   = (lane & 7) * 8;
    const int s0k   = (lane >> 4) * 8;
    const int koff0 = s0k ^ sw3;
    const int koff1 = (s0k | 32) ^ sw3;
    const int aoff  = (wm * (BM / WM) + (lane & 15)) * 64;
    const int boff  = (wn * (BN / WN) + (lane & 15)) * 64;

    auto stage = [&](int slot, int t) {
        #pragma unroll
        for (int i = 0; i < LA; ++i) {
            int c = i * THREADS + tid; int r = c >> 3;
            int c8 = ((c & 7) * 8) ^ ((r & 7) * 8);
            GLOAD16(A + (size_t)(row0 + r) * K + t * 64 + c8, &sA[slot][c * 8]);
        }
        #pragma unroll
        for (int i = 0; i < LB; ++i) {
            int c = i * THREADS + tid; int r = c >> 3;
            int c8 = ((c & 7) * 8) ^ ((r & 7) * 8);
            GLOAD16(B + (size_t)(col0 + r) * K + t * 64 + c8, &sB[slot][c * 8]);
        }
    };

    f32x4 acc[MI][NI] = {};

    stage(0, 0);
    WAITV0; BAR;

    for (int j = 0; j < nt; ++j) {
        const int s = j & 1;
        if (j + 1 < nt) stage(s ^ 1, j + 1);     // issue early, drain at tile end
        const bf16* sa = sA[s];
        const bf16* sb = sB[s];
        bf16x8 a[MI][2], b[NI][2];
        #pragma unroll
        for (int mi = 0; mi < MI; ++mi) {
            a[mi][0] = *(const bf16x8*)&sa[aoff + mi * 1024 + koff0];
            a[mi][1] = *(const bf16x8*)&sa[aoff + mi * 1024 + koff1];
        }
        #pragma unroll
        for (int ni = 0; ni < NI; ++ni) {
            b[ni][0] = *(const bf16x8*)&sb[boff + ni * 1024 + koff0];
            b[ni][1] = *(const bf16x8*)&sb[boff + ni * 1024 + koff1];
        }
        __builtin_amdgcn_s_setprio(1);
        #pragma unroll
        for (int mi = 0; mi < MI; ++mi)
            #pragma unroll
            for (int ni = 0; ni < NI; ++ni) {
                acc[mi][ni] = MFMA16(a[mi][0], b[ni][0], acc[mi][ni]);
                acc[mi][ni] = MFMA16(a[mi][1], b[ni][1], acc[mi][ni]);
            }
        __builtin_amdgcn_s_setprio(0);
        WAITV0;    // next tile fully landed (memory-clobber asm also fences reordering)
        BAR;
    }

    const int crow = row0 + wm * (BM / WM) + (lane >> 4) * 4;
    const int ccol = col0 + wn * (BN / WN) + (lane & 15);
    #pragma unroll
    for (int mi = 0; mi < MI; ++mi)
        #pragma unroll
        for (int ni = 0; ni < NI; ++ni)
            #pragma unroll
            for (int r = 0; r < 4; ++r)
                C[(size_t)(crow + mi * 16 + r) * N + ccol + ni * 16] = (CT)acc[mi][ni][r];
}

// ---------------- fused f32 -> bf16 bulk convert, 16 elems/thread ----------------
__global__ __launch_bounds__(256) void cvt3_k(const float* __restrict__ x,
                                              const float* __restrict__ wq,
                                              const float* __restrict__ wo,
                                              bf16* __restrict__ xbf,
                                              bf16* __restrict__ wqkv,
                                              bf16* __restrict__ wout) {
    int i = blockIdx.x * 256 + threadIdx.x;          // 0 .. 524287 chunks of 16
    const float* in; bf16* out; int off;
    if (i < 262144)       { in = x;  out = xbf;  off = i; }
    else if (i < 458752)  { in = wq; out = wqkv; off = i - 262144; }
    else                  { in = wo; out = wout; off = i - 458752; }
    const float* p = in + (size_t)off * 16;
    #pragma unroll
    for (int half = 0; half < 2; ++half) {
        f32x4 a = *(const f32x4*)(p + half * 8);
        f32x4 b = *(const f32x4*)(p + half * 8 + 4);
        bf16x8 o;
        o[0] = (bf16)a[0]; o[1] = (bf16)a[1]; o[2] = (bf16)a[2]; o[3] = (bf16)a[3];
        o[4] = (bf16)b[0]; o[5] = (bf16)b[1]; o[6] = (bf16)b[2]; o[7] = (bf16)b[3];
        *(bf16x8*)(out + (size_t)off * 16 + half * 8) = o;
    }
}

// ---- fused: blocks 0-255 = q row-softmax; blocks 256-767 = exp(k) partial sums ----
// scanA now 64 segments/bh (2048 chains, 32 t each) for 2x scanB parallelism.
__global__ __launch_bounds__(256) void qsA_k(bf16* __restrict__ qkv, float* __restrict__ part) {
    if (blockIdx.x < 256) {
        int tg = blockIdx.x * 256 + threadIdx.x;   // 0..65535
        int h = tg & 15, r = tg >> 4;
        bf16* q = qkv + (size_t)r * 3072 + h * 64;
        bf16x8 buf[8];
        float v[64];
        #pragma unroll
        for (int i = 0; i < 8; ++i) buf[i] = *(const bf16x8*)(q + i * 8);
        float m = -3.0e38f;
        #pragma unroll
        for (int i = 0; i < 8; ++i)
            #pragma unroll
            for (int e = 0; e < 8; ++e) { v[i * 8 + e] = (float)buf[i][e]; m = fmaxf(m, v[i * 8 + e]); }
        float s = 0.f;
        #pragma unroll
        for (int i = 0; i < 64; ++i) { v[i] = __expf(v[i] - m); s += v[i]; }
        float inv = 0.125f / s;
        #pragma unroll
        for (int i = 0; i < 8; ++i) {
            bf16x8 o;
            #pragma unroll
            for (int e = 0; e < 8; ++e) o[e] = (bf16)(v[i * 8 + e] * inv);
            *(bf16x8*)(q + i * 8) = o;
        }
    } else {
        int blk = (blockIdx.x - 256) * 4 + (threadIdx.x >> 6);   // 0..2047
        int bh = blk >> 6, seg = blk & 63;
        int b = bh >> 4, h = bh & 15;
        int c = threadIdx.x & 63;
        const bf16* kb = qkv + (size_t)b * 2048 * 3072 + 1024 + h * 64 + c;
        float s = 0.f;
        for (int t0 = seg * 32; t0 < seg * 32 + 32; t0 += 8) {
            float e[8];
            #pragma unroll
            for (int u = 0; u < 8; ++u) e[u] = (float)kb[(size_t)(t0 + u) * 3072];
            #pragma unroll
            for (int u = 0; u < 8; ++u) s += __expf(e[u]);
        }
        part[blk * 64 + c] = s;
    }
}

// -------- carry-in sweep: q -> qn = qsm/(kcum+eps), k -> exp(k), in place, 8-batched --------
__global__ __launch_bounds__(64) void scanB_k(bf16* __restrict__ qkv, const float* __restrict__ part) {
    int blk = blockIdx.x;
    int bh = blk >> 6, seg = blk & 63;
    int b = bh >> 4, h = bh & 15;
    int c = threadIdx.x;
    bf16* qb = qkv + (size_t)b * 2048 * 3072 + h * 64 + c;
    bf16* kb = qb + 1024;
    float run = 0.f;
    for (int i = 0; i < seg; ++i) run += part[(bh * 64 + i) * 64 + c];
    for (int t0 = seg * 32; t0 < seg * 32 + 32; t0 += 8) {
        float e[8], qv[8];
        #pragma unroll
        for (int u = 0; u < 8; ++u) e[u] = (float)kb[(size_t)(t0 + u) * 3072];
        #pragma unroll
        for (int u = 0; u < 8; ++u) qv[u] = (float)qb[(size_t)(t0 + u) * 3072];
        #pragma unroll
        for (int u = 0; u < 8; ++u) {
            e[u] = __expf(e[u]);
            run += e[u];
            qv[u] = qv[u] / (run + 1e-9f);
        }
        #pragma unroll
        for (int u = 0; u < 8; ++u) {
            qb[(size_t)(t0 + u) * 3072] = (bf16)qv[u];
            kb[(size_t)(t0 + u) * 3072] = (bf16)e[u];
        }
    }
}

// -------- phase 1: per-chunk KV state  Wc[d][c] = sum_s V[s,d]*kexp[s,c]  (f32) --------
__global__ __launch_bounds__(256) void kvchunk_k(const bf16* __restrict__ qkv, float* __restrict__ Wc) {
    __shared__ bf16 KT[64][136];
    __shared__ bf16 VT[64][136];
    const int blk = blockIdx.x, bh = blk >> 4, j = blk & 15;
    const int b = bh >> 4, h = bh & 15;
    const int tid = threadIdx.x, lane = tid & 63, w = tid >> 6;
    const bf16* kbase = qkv + (size_t)(b * 2048 + j * 128) * 3072 + 1024 + h * 64;
    const bf16* vbase = kbase + 1024;

    #pragma unroll
    for (int i = 0; i < 4; ++i) {
        int idx = i * 256 + tid;
        int s = idx >> 3, cg = (idx & 7) * 8;
        bf16x8 k8 = *(const bf16x8*)(kbase + (size_t)s * 3072 + cg);
        bf16x8 v8 = *(const bf16x8*)(vbase + (size_t)s * 3072 + cg);
        #pragma unroll
        for (int e = 0; e < 8; ++e) {
            int d = cg + e;
            int sw2 = s ^ (((d >> 3) & 7) << 3);
            KT[d][sw2] = k8[e];
            VT[d][sw2] = v8[e];
        }
    }
    __syncthreads();

    f32x4 acc[4] = {};
    const int dr = w * 16 + (lane & 15);
    const int swd = ((dr >> 3) & 7) << 3;
    #pragma unroll
    for (int ks = 0; ks < 4; ++ks) {
        const int sc = ks * 32 + (lane >> 4) * 8;
        bf16x8 av = *(const bf16x8*)&VT[dr][sc ^ swd];
        #pragma unroll
        for (int ni = 0; ni < 4; ++ni) {
            int cr = ni * 16 + (lane & 15);
            bf16x8 bk = *(const bf16x8*)&KT[cr][sc ^ (((cr >> 3) & 7) << 3)];
            acc[ni] = MFMA16(av, bk, acc[ni]);
        }
    }
    float* out = Wc + (size_t)blk * 4096;
    const int dw = w * 16 + (lane >> 4) * 4;
    #pragma unroll
    for (int ni = 0; ni < 4; ++ni)
        #pragma unroll
        for (int r = 0; r < 4; ++r)
            out[(dw + r) * 64 + ni * 16 + (lane & 15)] = acc[ni][r];
}

// -------- phase 2: exclusive cumsum of chunk states across 16 chunks, f32 -> bf16 --------
__global__ __launch_bounds__(256) void kvscan_k(const float* __restrict__ Wc, bf16* __restrict__ Wpre) {
    int e = blockIdx.x * 256 + threadIdx.x;     // 131072
    int bh = e >> 12, off = e & 4095;
    float run = 0.f;
    #pragma unroll
    for (int j = 0; j < 16; ++j) {
        size_t idx = (size_t)(bh * 16 + j) * 4096 + off;
        Wpre[idx] = (bf16)run;
        run += Wc[idx];
    }
}

// -------- phase 3: O = qn @ Wpre (far) + masked (qn@K^T) @ V (near), causal wave-skip --------
__global__ __launch_bounds__(256) void attn2_k(const bf16* __restrict__ qkv,
                                               const bf16* __restrict__ Wpre,
                                               bf16* __restrict__ xo) {
    __shared__ bf16 Ks[128][72];
    __shared__ bf16 VTs[64][136];
    __shared__ bf16 Ss[128][136];
    const int bh = blockIdx.y, b = bh >> 4, h = bh & 15;
    const int ti = blockIdx.x, t0 = ti * 128;
    const int tid = threadIdx.x, lane = tid & 63, w = tid >> 6;
    const bf16* qn = qkv + (size_t)b * 2048 * 3072 + h * 64;
    const bf16* ke = qn + 1024;
    const bf16* vv = qn + 2048;

    bf16x8 qf[2][2];
    #pragma unroll
    for (int mi = 0; mi < 2; ++mi)
        #pragma unroll
        for (int kk = 0; kk < 2; ++kk)
            qf[mi][kk] = *(const bf16x8*)(qn + (size_t)(t0 + w * 32 + mi * 16 + (lane & 15)) * 3072
                                          + kk * 32 + (lane >> 4) * 8);
    const bf16* wp = Wpre + (size_t)(bh * 16 + ti) * 4096;
    bf16x8 wf[4][2];
    #pragma unroll
    for (int ni = 0; ni < 4; ++ni)
        #pragma unroll
        for (int kk = 0; kk < 2; ++kk)
            wf[ni][kk] = *(const bf16x8*)(wp + (ni * 16 + (lane & 15)) * 64 + kk * 32 + (lane >> 4) * 8);

    #pragma unroll
    for (int i = 0; i < 4; ++i) {
        int idx = i * 256 + tid;
        int s = idx >> 3, cg = (idx & 7) * 8;
        *(f32x4*)&Ks[s][cg] = *(const f32x4*)(ke + (size_t)(t0 + s) * 3072 + cg);
        bf16x8 v8 = *(const bf16x8*)(vv + (size_t)(t0 + s) * 3072 + cg);
        #pragma unroll
        for (int e = 0; e < 8; ++e) {
            int d = cg + e;
            VTs[d][s ^ (((d >> 3) & 7) << 3)] = v8[e];
        }
    }
    __syncthreads();

    // far field
    f32x4 accO[2][4] = {};
    #pragma unroll
    for (int kk = 0; kk < 2; ++kk)
        #pragma unroll
        for (int mi = 0; mi < 2; ++mi)
            #pragma unroll
            for (int ni = 0; ni < 4; ++ni)
                accO[mi][ni] = MFMA16(qf[mi][kk], wf[ni][kk], accO[mi][ni]);

    // near: S = qn @ K^T — wave w needs only s-cols < 32*(w+1)  (wave-uniform skip)
    const int nq = 2 * (w + 1);
    f32x4 accS[2][8] = {};
    #pragma unroll
    for (int kk = 0; kk < 2; ++kk) {
        const int kc = kk * 32 + (lane >> 4) * 8;
        bf16x8 kf[8];
        #pragma unroll
        for (int ni = 0; ni < 8; ++ni)
            if (ni < nq) kf[ni] = *(const bf16x8*)&Ks[ni * 16 + (lane & 15)][kc];
        #pragma unroll
        for (int mi = 0; mi < 2; ++mi)
            #pragma unroll
            for (int ni = 0; ni < 8; ++ni)
                if (ni < nq) accS[mi][ni] = MFMA16(qf[mi][kk], kf[ni], accS[mi][ni]);
    }
    #pragma unroll
    for (int mi = 0; mi < 2; ++mi)
        #pragma unroll
        for (int ni = 0; ni < 8; ++ni)
            if (ni < nq) {
                const int tb = w * 32 + mi * 16 + (lane >> 4) * 4;
                const int sb = ni * 16 + (lane & 15);
                #pragma unroll
                for (int r = 0; r < 4; ++r) {
                    float sv = accS[mi][ni][r];
                    if (sb > tb + r) sv = 0.f;
                    Ss[tb + r][sb] = (bf16)sv;
                }
            }
    // no __syncthreads: Ss rows are wave-private (written and read by the same wave)

    // O += S @ V — wave w needs only k-steps <= w
    #pragma unroll
    for (int ks = 0; ks < 4; ++ks)
        if (ks <= w) {
            const int kc = ks * 32 + (lane >> 4) * 8;
            bf16x8 sf[2], vf[4];
            #pragma unroll
            for (int mi = 0; mi < 2; ++mi) sf[mi] = *(const bf16x8*)&Ss[w * 32 + mi * 16 + (lane & 15)][kc];
            #pragma unroll
            for (int ni = 0; ni < 4; ++ni) {
                int d = ni * 16 + (lane & 15);
                vf[ni] = *(const bf16x8*)&VTs[d][kc ^ (((d >> 3) & 7) << 3)];
            }
            #pragma unroll
            for (int mi = 0; mi < 2; ++mi)
                #pragma unroll
                for (int ni = 0; ni < 4; ++ni)
                    accO[mi][ni] = MFMA16(sf[mi], vf[ni], accO[mi][ni]);
        }

    #pragma unroll
    for (int mi = 0; mi < 2; ++mi)
        #pragma unroll
        for (int ni = 0; ni < 4; ++ni) {
            const int trow = t0 + w * 32 + mi * 16 + (lane >> 4) * 4;
            const int d = ni * 16 + (lane & 15);
            #pragma unroll
            for (int r = 0; r < 4; ++r)
                xo[(size_t)(b * 2048 + trow + r) * 1024 + h * 64 + d] = (bf16)accO[mi][ni][r];
        }
}

extern "C" void kernel_launch(void* const* d_in, const int* in_sizes, int n_in,
                              void* d_out, int out_size, void* d_ws, size_t ws_size,
                              hipStream_t stream) {
    const float* x  = (const float*)d_in[0];   // (2,2048,1024)
    const float* wq = (const float*)d_in[1];   // (3072,1024)
    const float* wo = (const float*)d_in[2];   // (1024,1024)

    char* ws = (char*)d_ws;
    bf16*  xbf  = (bf16*)(ws);
    float* Wc   = (float*)(ws);
    bf16*  xo   = (bf16*)(ws);
    bf16*  wqkv = (bf16*)(ws + (8u << 20));
    bf16*  Wpre = (bf16*)(ws + (8u << 20));
    bf16*  wout = (bf16*)(ws + (14u << 20));
    bf16*  qkv  = (bf16*)(ws + (16u << 20));   // 24MB
    float* part = (float*)(ws + (40u << 20));  // 512KB

    cvt3_k<<<2048, 256, 0, stream>>>(x, wq, wo, xbf, wqkv, wout);

    // 128x192 tile, 80KiB LDS -> 2 blocks/CU; grid 16x32 = 512 = exactly 2/CU
    gemm2ph<bf16, 128, 192, 2, 4, 4><<<dim3(16, 32), 512, 0, stream>>>(xbf, wqkv, qkv, 4096, 3072, 1024);

    qsA_k<<<768, 256, 0, stream>>>(qkv, part);
    scanB_k<<<2048, 64, 0, stream>>>(qkv, part);

    kvchunk_k<<<512, 256, 0, stream>>>(qkv, Wc);
    kvscan_k<<<512, 256, 0, stream>>>(Wc, Wpre);
    attn2_k<<<dim3(16, 32), 256, 0, stream>>>(qkv, Wpre, xo);

    gemm2ph<float, 128, 64, 2, 2, 2><<<dim3(16, 32), 256, 0, stream>>>(xo, wout, (float*)d_out, 4096, 1024, 1024);
}

// Round 12
// 104.383 us; speedup vs baseline: 1.2017x; 1.0377x over previous
//
#include <hip/hip_runtime.h>

typedef __bf16 bf16;
typedef __bf16 bf16x8 __attribute__((ext_vector_type(8)));
typedef float  f32x4  __attribute__((ext_vector_type(4)));

#define MFMA16(a, b, c) __builtin_amdgcn_mfma_f32_16x16x32_bf16((a), (b), (c), 0, 0, 0)

#define GLOAD16(gp, lp) __builtin_amdgcn_global_load_lds( \
    (const __attribute__((address_space(1))) void*)(gp),  \
    (__attribute__((address_space(3))) void*)(lp), 16, 0, 0)

#define BAR __builtin_amdgcn_s_barrier()
#define WAITV0 asm volatile("s_waitcnt vmcnt(0)" ::: "memory")

// ==== unified 2-phase double-buffered NT GEMM ====
// C(MxN) = A(MxK) @ B(NxK)^T; BK=64; 3-bit XOR LDS swizzle; XCD block swizzle;
// per K-tile: stage(next) -> read all frags -> MFMA -> vmcnt(0) -> 1 barrier.
template <typename CT, int BM, int BN, int WM, int WN, int MINW>
__global__ __launch_bounds__(WM * WN * 64, MINW) void gemm2ph(const bf16* __restrict__ A,
                                                              const bf16* __restrict__ B,
                                                              CT* __restrict__ C,
                                                              int M, int N, int K) {
    constexpr int THREADS = WM * WN * 64;
    constexpr int MI = BM / WM / 16, NI = BN / WN / 16;
    constexpr int LA = BM * 8 / THREADS, LB = BN * 8 / THREADS;
    __shared__ bf16 sA[2][BM * 64];
    __shared__ bf16 sB[2][BN * 64];
    const int tid = threadIdx.x, lane = tid & 63, w = tid >> 6;
    const int wm = w / WN, wn = w % WN;

    // XCD-aware bijective block swizzle (nwg % 8 == 0)
    const int nwg = gridDim.x * gridDim.y;
    const int lin = blockIdx.y * gridDim.x + blockIdx.x;
    const int cpx = nwg >> 3;
    const int swzb = (lin & 7) * cpx + (lin >> 3);
    const int row0 = (swzb / gridDim.x) * BM, col0 = (swzb % gridDim.x) * BN;
    const int nt = K >> 6;

    // 3-bit row-XOR swizzle: LDS[r][c] holds global[r][c ^ (r&7)*8]
    const int sw3   = (lane & 7) * 8;
    const int s0k   = (lane >> 4) * 8;
    const int koff0 = s0k ^ sw3;
    const int koff1 = (s0k | 32) ^ sw3;
    const int aoff  = (wm * (BM / WM) + (lane & 15)) * 64;
    const int boff  = (wn * (BN / WN) + (lane & 15)) * 64;

    auto stage = [&](int slot, int t) {
        #pragma unroll
        for (int i = 0; i < LA; ++i) {
            int c = i * THREADS + tid; int r = c >> 3;
            int c8 = ((c & 7) * 8) ^ ((r & 7) * 8);
            GLOAD16(A + (size_t)(row0 + r) * K + t * 64 + c8, &sA[slot][c * 8]);
        }
        #pragma unroll
        for (int i = 0; i < LB; ++i) {
            int c = i * THREADS + tid; int r = c >> 3;
            int c8 = ((c & 7) * 8) ^ ((r & 7) * 8);
            GLOAD16(B + (size_t)(col0 + r) * K + t * 64 + c8, &sB[slot][c * 8]);
        }
    };

    f32x4 acc[MI][NI] = {};

    stage(0, 0);
    WAITV0; BAR;

    for (int j = 0; j < nt; ++j) {
        const int s = j & 1;
        if (j + 1 < nt) stage(s ^ 1, j + 1);     // issue early, drain at tile end
        const bf16* sa = sA[s];
        const bf16* sb = sB[s];
        bf16x8 a[MI][2], b[NI][2];
        #pragma unroll
        for (int mi = 0; mi < MI; ++mi) {
            a[mi][0] = *(const bf16x8*)&sa[aoff + mi * 1024 + koff0];
            a[mi][1] = *(const bf16x8*)&sa[aoff + mi * 1024 + koff1];
        }
        #pragma unroll
        for (int ni = 0; ni < NI; ++ni) {
            b[ni][0] = *(const bf16x8*)&sb[boff + ni * 1024 + koff0];
            b[ni][1] = *(const bf16x8*)&sb[boff + ni * 1024 + koff1];
        }
        __builtin_amdgcn_s_setprio(1);
        #pragma unroll
        for (int mi = 0; mi < MI; ++mi)
            #pragma unroll
            for (int ni = 0; ni < NI; ++ni) {
                acc[mi][ni] = MFMA16(a[mi][0], b[ni][0], acc[mi][ni]);
                acc[mi][ni] = MFMA16(a[mi][1], b[ni][1], acc[mi][ni]);
            }
        __builtin_amdgcn_s_setprio(0);
        WAITV0;    // next tile fully landed (memory-clobber asm also fences reordering)
        BAR;
    }

    const int crow = row0 + wm * (BM / WM) + (lane >> 4) * 4;
    const int ccol = col0 + wn * (BN / WN) + (lane & 15);
    #pragma unroll
    for (int mi = 0; mi < MI; ++mi)
        #pragma unroll
        for (int ni = 0; ni < NI; ++ni)
            #pragma unroll
            for (int r = 0; r < 4; ++r)
                C[(size_t)(crow + mi * 16 + r) * N + ccol + ni * 16] = (CT)acc[mi][ni][r];
}

// ---------------- fused f32 -> bf16 bulk convert, 16 elems/thread ----------------
__global__ __launch_bounds__(256) void cvt3_k(const float* __restrict__ x,
                                              const float* __restrict__ wq,
                                              const float* __restrict__ wo,
                                              bf16* __restrict__ xbf,
                                              bf16* __restrict__ wqkv,
                                              bf16* __restrict__ wout) {
    int i = blockIdx.x * 256 + threadIdx.x;          // 0 .. 524287 chunks of 16
    const float* in; bf16* out; int off;
    if (i < 262144)       { in = x;  out = xbf;  off = i; }
    else if (i < 458752)  { in = wq; out = wqkv; off = i - 262144; }
    else                  { in = wo; out = wout; off = i - 458752; }
    const float* p = in + (size_t)off * 16;
    #pragma unroll
    for (int half = 0; half < 2; ++half) {
        f32x4 a = *(const f32x4*)(p + half * 8);
        f32x4 b = *(const f32x4*)(p + half * 8 + 4);
        bf16x8 o;
        o[0] = (bf16)a[0]; o[1] = (bf16)a[1]; o[2] = (bf16)a[2]; o[3] = (bf16)a[3];
        o[4] = (bf16)b[0]; o[5] = (bf16)b[1]; o[6] = (bf16)b[2]; o[7] = (bf16)b[3];
        *(bf16x8*)(out + (size_t)off * 16 + half * 8) = o;
    }
}

// ---- fused: blocks 0-255 = q row-softmax; blocks 256-767 = exp(k) partial sums ----
// partA: 64 segments/bh of 32 rows each -> part[(bh*64+seg)*64+c].
__global__ __launch_bounds__(256) void qsA_k(bf16* __restrict__ qkv, float* __restrict__ part) {
    if (blockIdx.x < 256) {
        int tg = blockIdx.x * 256 + threadIdx.x;   // 0..65535
        int h = tg & 15, r = tg >> 4;
        bf16* q = qkv + (size_t)r * 3072 + h * 64;
        bf16x8 buf[8];
        float v[64];
        #pragma unroll
        for (int i = 0; i < 8; ++i) buf[i] = *(const bf16x8*)(q + i * 8);
        float m = -3.0e38f;
        #pragma unroll
        for (int i = 0; i < 8; ++i)
            #pragma unroll
            for (int e = 0; e < 8; ++e) { v[i * 8 + e] = (float)buf[i][e]; m = fmaxf(m, v[i * 8 + e]); }
        float s = 0.f;
        #pragma unroll
        for (int i = 0; i < 64; ++i) { v[i] = __expf(v[i] - m); s += v[i]; }
        float inv = 0.125f / s;
        #pragma unroll
        for (int i = 0; i < 8; ++i) {
            bf16x8 o;
            #pragma unroll
            for (int e = 0; e < 8; ++e) o[e] = (bf16)(v[i * 8 + e] * inv);
            *(bf16x8*)(q + i * 8) = o;
        }
    } else {
        int blk = (blockIdx.x - 256) * 4 + (threadIdx.x >> 6);   // 0..2047
        int bh = blk >> 6, seg = blk & 63;
        int b = bh >> 4, h = bh & 15;
        int c = threadIdx.x & 63;
        const bf16* kb = qkv + (size_t)b * 2048 * 3072 + 1024 + h * 64 + c;
        float s = 0.f;
        for (int t0 = seg * 32; t0 < seg * 32 + 32; t0 += 8) {
            float e[8];
            #pragma unroll
            for (int u = 0; u < 8; ++u) e[u] = (float)kb[(size_t)(t0 + u) * 3072];
            #pragma unroll
            for (int u = 0; u < 8; ++u) s += __expf(e[u]);
        }
        part[blk * 64 + c] = s;
    }
}

// ==== fused scan + chunk-state: one block per (bh, 128-row chunk j) ====
// Scan phase: q -> qn = qsm/(kcum+eps), k -> exp(k), in place (global) AND kexp
// into transposed LDS KT. MFMA phase: Wc[d][c] = sum_s V[s,d]*kexp[s,c].
__global__ __launch_bounds__(256) void mid_k(bf16* __restrict__ qkv,
                                             const float* __restrict__ part,
                                             float* __restrict__ Wc) {
    __shared__ bf16 KT[64][136];
    __shared__ bf16 VT[64][136];
    const int blk = blockIdx.x, bh = blk >> 4, j = blk & 15;
    const int b = bh >> 4, h = bh & 15;
    const int tid = threadIdx.x, lane = tid & 63, w = tid >> 6;
    bf16* qb = qkv + (size_t)(b * 2048 + j * 128) * 3072 + h * 64;   // chunk-local rows
    bf16* kb = qb + 1024;
    const bf16* vb = qb + 2048;

    // stage V transposed + swizzled
    #pragma unroll
    for (int i = 0; i < 4; ++i) {
        int idx = i * 256 + tid;
        int s = idx >> 3, cg = (idx & 7) * 8;
        bf16x8 v8 = *(const bf16x8*)(vb + (size_t)s * 3072 + cg);
        #pragma unroll
        for (int e = 0; e < 8; ++e) {
            int d = cg + e;
            VT[d][s ^ (((d >> 3) & 7) << 3)] = v8[e];
        }
    }

    // scan phase: thread (c, sg) owns rows sg*32 .. sg*32+31 of this chunk
    {
        const int c = tid & 63, sg = tid >> 6;
        const int swc = ((c >> 3) & 7) << 3;
        const int segglob = j * 4 + sg;
        float run = 0.f;
        for (int i = 0; i < segglob; ++i) run += part[(bh * 64 + i) * 64 + c];
        for (int t0 = sg * 32; t0 < sg * 32 + 32; t0 += 8) {
            float e[8], qv[8];
            #pragma unroll
            for (int u = 0; u < 8; ++u) e[u] = (float)kb[(size_t)(t0 + u) * 3072 + c];
            #pragma unroll
            for (int u = 0; u < 8; ++u) qv[u] = (float)qb[(size_t)(t0 + u) * 3072 + c];
            #pragma unroll
            for (int u = 0; u < 8; ++u) {
                e[u] = __expf(e[u]);
                run += e[u];
                qv[u] = qv[u] / (run + 1e-9f);
            }
            #pragma unroll
            for (int u = 0; u < 8; ++u) {
                bf16 eb = (bf16)e[u];
                qb[(size_t)(t0 + u) * 3072 + c] = (bf16)qv[u];
                kb[(size_t)(t0 + u) * 3072 + c] = eb;
                KT[c][(t0 + u) ^ swc] = eb;
            }
        }
    }
    __syncthreads();

    // MFMA phase: Wc = V^T x K^T over the chunk's 128 positions
    f32x4 acc[4] = {};
    const int dr = w * 16 + (lane & 15);
    const int swd = ((dr >> 3) & 7) << 3;
    #pragma unroll
    for (int ks = 0; ks < 4; ++ks) {
        const int sc = ks * 32 + (lane >> 4) * 8;
        bf16x8 av = *(const bf16x8*)&VT[dr][sc ^ swd];
        #pragma unroll
        for (int ni = 0; ni < 4; ++ni) {
            int cr = ni * 16 + (lane & 15);
            bf16x8 bk = *(const bf16x8*)&KT[cr][sc ^ (((cr >> 3) & 7) << 3)];
            acc[ni] = MFMA16(av, bk, acc[ni]);
        }
    }
    float* out = Wc + (size_t)blk * 4096;
    const int dw = w * 16 + (lane >> 4) * 4;
    #pragma unroll
    for (int ni = 0; ni < 4; ++ni)
        #pragma unroll
        for (int r = 0; r < 4; ++r)
            out[(dw + r) * 64 + ni * 16 + (lane & 15)] = acc[ni][r];
}

// -------- exclusive cumsum of chunk states across 16 chunks, f32 -> bf16 --------
__global__ __launch_bounds__(256) void kvscan_k(const float* __restrict__ Wc, bf16* __restrict__ Wpre) {
    int e = blockIdx.x * 256 + threadIdx.x;     // 131072
    int bh = e >> 12, off = e & 4095;
    float run = 0.f;
    #pragma unroll
    for (int j = 0; j < 16; ++j) {
        size_t idx = (size_t)(bh * 16 + j) * 4096 + off;
        Wpre[idx] = (bf16)run;
        run += Wc[idx];
    }
}

// -------- O = qn @ Wpre (far) + masked (qn@K^T) @ V (near), causal wave-skip --------
__global__ __launch_bounds__(256) void attn2_k(const bf16* __restrict__ qkv,
                                               const bf16* __restrict__ Wpre,
                                               bf16* __restrict__ xo) {
    __shared__ bf16 Ks[128][72];
    __shared__ bf16 VTs[64][136];
    __shared__ bf16 Ss[128][136];
    const int bh = blockIdx.y, b = bh >> 4, h = bh & 15;
    const int ti = blockIdx.x, t0 = ti * 128;
    const int tid = threadIdx.x, lane = tid & 63, w = tid >> 6;
    const bf16* qn = qkv + (size_t)b * 2048 * 3072 + h * 64;
    const bf16* ke = qn + 1024;
    const bf16* vv = qn + 2048;

    bf16x8 qf[2][2];
    #pragma unroll
    for (int mi = 0; mi < 2; ++mi)
        #pragma unroll
        for (int kk = 0; kk < 2; ++kk)
            qf[mi][kk] = *(const bf16x8*)(qn + (size_t)(t0 + w * 32 + mi * 16 + (lane & 15)) * 3072
                                          + kk * 32 + (lane >> 4) * 8);
    const bf16* wp = Wpre + (size_t)(bh * 16 + ti) * 4096;
    bf16x8 wf[4][2];
    #pragma unroll
    for (int ni = 0; ni < 4; ++ni)
        #pragma unroll
        for (int kk = 0; kk < 2; ++kk)
            wf[ni][kk] = *(const bf16x8*)(wp + (ni * 16 + (lane & 15)) * 64 + kk * 32 + (lane >> 4) * 8);

    #pragma unroll
    for (int i = 0; i < 4; ++i) {
        int idx = i * 256 + tid;
        int s = idx >> 3, cg = (idx & 7) * 8;
        *(f32x4*)&Ks[s][cg] = *(const f32x4*)(ke + (size_t)(t0 + s) * 3072 + cg);
        bf16x8 v8 = *(const bf16x8*)(vv + (size_t)(t0 + s) * 3072 + cg);
        #pragma unroll
        for (int e = 0; e < 8; ++e) {
            int d = cg + e;
            VTs[d][s ^ (((d >> 3) & 7) << 3)] = v8[e];
        }
    }
    __syncthreads();

    // far field
    f32x4 accO[2][4] = {};
    #pragma unroll
    for (int kk = 0; kk < 2; ++kk)
        #pragma unroll
        for (int mi = 0; mi < 2; ++mi)
            #pragma unroll
            for (int ni = 0; ni < 4; ++ni)
                accO[mi][ni] = MFMA16(qf[mi][kk], wf[ni][kk], accO[mi][ni]);

    // near: S = qn @ K^T — wave w needs only s-cols < 32*(w+1)
    const int nq = 2 * (w + 1);
    f32x4 accS[2][8] = {};
    #pragma unroll
    for (int kk = 0; kk < 2; ++kk) {
        const int kc = kk * 32 + (lane >> 4) * 8;
        bf16x8 kf[8];
        #pragma unroll
        for (int ni = 0; ni < 8; ++ni)
            if (ni < nq) kf[ni] = *(const bf16x8*)&Ks[ni * 16 + (lane & 15)][kc];
        #pragma unroll
        for (int mi = 0; mi < 2; ++mi)
            #pragma unroll
            for (int ni = 0; ni < 8; ++ni)
                if (ni < nq) accS[mi][ni] = MFMA16(qf[mi][kk], kf[ni], accS[mi][ni]);
    }
    #pragma unroll
    for (int mi = 0; mi < 2; ++mi)
        #pragma unroll
        for (int ni = 0; ni < 8; ++ni)
            if (ni < nq) {
                const int tb = w * 32 + mi * 16 + (lane >> 4) * 4;
                const int sb = ni * 16 + (lane & 15);
                #pragma unroll
                for (int r = 0; r < 4; ++r) {
                    float sv = accS[mi][ni][r];
                    if (sb > tb + r) sv = 0.f;
                    Ss[tb + r][sb] = (bf16)sv;
                }
            }
    // no __syncthreads: Ss rows are wave-private

    // O += S @ V — wave w needs only k-steps <= w
    #pragma unroll
    for (int ks = 0; ks < 4; ++ks)
        if (ks <= w) {
            const int kc = ks * 32 + (lane >> 4) * 8;
            bf16x8 sf[2], vf[4];
            #pragma unroll
            for (int mi = 0; mi < 2; ++mi) sf[mi] = *(const bf16x8*)&Ss[w * 32 + mi * 16 + (lane & 15)][kc];
            #pragma unroll
            for (int ni = 0; ni < 4; ++ni) {
                int d = ni * 16 + (lane & 15);
                vf[ni] = *(const bf16x8*)&VTs[d][kc ^ (((d >> 3) & 7) << 3)];
            }
            #pragma unroll
            for (int mi = 0; mi < 2; ++mi)
                #pragma unroll
                for (int ni = 0; ni < 4; ++ni)
                    accO[mi][ni] = MFMA16(sf[mi], vf[ni], accO[mi][ni]);
        }

    #pragma unroll
    for (int mi = 0; mi < 2; ++mi)
        #pragma unroll
        for (int ni = 0; ni < 4; ++ni) {
            const int trow = t0 + w * 32 + mi * 16 + (lane >> 4) * 4;
            const int d = ni * 16 + (lane & 15);
            #pragma unroll
            for (int r = 0; r < 4; ++r)
                xo[(size_t)(b * 2048 + trow + r) * 1024 + h * 64 + d] = (bf16)accO[mi][ni][r];
        }
}

extern "C" void kernel_launch(void* const* d_in, const int* in_sizes, int n_in,
                              void* d_out, int out_size, void* d_ws, size_t ws_size,
                              hipStream_t stream) {
    const float* x  = (const float*)d_in[0];   // (2,2048,1024)
    const float* wq = (const float*)d_in[1];   // (3072,1024)
    const float* wo = (const float*)d_in[2];   // (1024,1024)

    char* ws = (char*)d_ws;
    bf16*  xbf  = (bf16*)(ws);
    float* Wc   = (float*)(ws);
    bf16*  xo   = (bf16*)(ws);
    bf16*  wqkv = (bf16*)(ws + (8u << 20));
    bf16*  Wpre = (bf16*)(ws + (8u << 20));
    bf16*  wout = (bf16*)(ws + (14u << 20));
    bf16*  qkv  = (bf16*)(ws + (16u << 20));   // 24MB
    float* part = (float*)(ws + (40u << 20));  // 512KB

    cvt3_k<<<2048, 256, 0, stream>>>(x, wq, wo, xbf, wqkv, wout);

    // 128x192 tile, 80KiB LDS -> 2 blocks/CU; grid 16x32 = 512 = exactly 2/CU
    gemm2ph<bf16, 128, 192, 2, 4, 4><<<dim3(16, 32), 512, 0, stream>>>(xbf, wqkv, qkv, 4096, 3072, 1024);

    qsA_k<<<768, 256, 0, stream>>>(qkv, part);

    mid_k<<<512, 256, 0, stream>>>(qkv, part, Wc);
    kvscan_k<<<512, 256, 0, stream>>>(Wc, Wpre);
    attn2_k<<<dim3(16, 32), 256, 0, stream>>>(qkv, Wpre, xo);

    gemm2ph<float, 128, 64, 2, 2, 2><<<dim3(16, 32), 256, 0, stream>>>(xo, wout, (float*)d_out, 4096, 1024, 1024);
}